// Round 4
// baseline (502.460 us; speedup 1.0000x reference)
//
#include <hip/hip_runtime.h>
#include <hip/hip_bf16.h>
#include <math.h>

#define BB 512
#define CC 50

// ---------------- zero-fill out[0 : 512*692*10) ----------------
__global__ void k_zero(float* __restrict__ out, int n4) {
  int i = blockIdx.x * 256 + threadIdx.x;
  if (i < n4) {
    float4 z = {0.f, 0.f, 0.f, 0.f};
    ((float4*)out)[i] = z;
  }
}

// ---------------- pack per-j head record: [w(50), b(1), l2col(10), pad(3)] = 64 floats ----------------
// Padded to 512 records; j in [500,512) is all-zero -> contributes exactly 0 to the head.
__global__ void k_pack(const float* __restrict__ l1w, const float* __restrict__ l1b,
                       const float* __restrict__ l2w, float* __restrict__ pack) {
  int idx = blockIdx.x * 256 + threadIdx.x;
  if (idx >= 512 * 64) return;
  int j = idx >> 6, s = idx & 63;
  float v = 0.f;
  if (j < 500) {
    if (s < 50) v = l1w[j * 50 + s];
    else if (s == 50) v = l1b[j];
    else if (s < 61) v = l2w[(s - 51) * 500 + j];
  }
  pack[idx] = v;
}

// ---------------- conv1 (1->50, 3x3) + relu + pool2 -> h1[512,50,13,13] ----------------
__global__ void k_conv1(const float* __restrict__ x, const float* __restrict__ w,
                        const float* __restrict__ bias, float* __restrict__ h1) {
  int idx = blockIdx.x * 256 + threadIdx.x;
  if (idx >= BB * CC * 169) return;
  int b = idx / (CC * 169);
  int rem = idx % (CC * 169);
  int c = rem / 169;
  int p = rem % 169;
  int py = p / 13, px = p % 13;
  const float* xi = x + b * 784;
  float wr[9];
#pragma unroll
  for (int i = 0; i < 9; i++) wr[i] = w[c * 9 + i];
  float m = -INFINITY;
#pragma unroll
  for (int dy = 0; dy < 2; dy++)
#pragma unroll
    for (int dx = 0; dx < 2; dx++) {
      int y0 = 2 * py + dy, x0 = 2 * px + dx;
      float s = 0.f;
#pragma unroll
      for (int ky = 0; ky < 3; ky++)
#pragma unroll
        for (int kx = 0; kx < 3; kx++)
          s += xi[(y0 + ky) * 28 + x0 + kx] * wr[ky * 3 + kx];
      m = fmaxf(m, s);
    }
  h1[idx] = fmaxf(m + bias[c], 0.f);
}

// ---------------- router 1: argmax over 3 logits of h1 flat (8450) ----------------
__global__ void k_d1(const float* __restrict__ h1, const float* __restrict__ w,
                     const float* __restrict__ bias, int* __restrict__ d1i,
                     float* __restrict__ outd1) {
  int b = blockIdx.x, t = threadIdx.x;
  const float* hb = h1 + b * 8450;
  float s0 = 0.f, s1 = 0.f, s2 = 0.f;
  for (int i = t; i < 8450; i += 256) {
    float v = hb[i];
    s0 += v * w[i];
    s1 += v * w[8450 + i];
    s2 += v * w[16900 + i];
  }
#pragma unroll
  for (int off = 32; off >= 1; off >>= 1) {
    s0 += __shfl_down(s0, off);
    s1 += __shfl_down(s1, off);
    s2 += __shfl_down(s2, off);
  }
  __shared__ float red[4][3];
  if ((t & 63) == 0) { red[t >> 6][0] = s0; red[t >> 6][1] = s1; red[t >> 6][2] = s2; }
  __syncthreads();
  if (t == 0) {
    float l0 = bias[0], l1v = bias[1], l2v = bias[2];
    for (int wv = 0; wv < 4; wv++) { l0 += red[wv][0]; l1v += red[wv][1]; l2v += red[wv][2]; }
    int idx = 0; float best = l0;
    if (l1v > best) { best = l1v; idx = 1; }
    if (l2v > best) { best = l2v; idx = 2; }
    d1i[b] = idx;
    outd1[b] = (float)idx;
  }
}

// ---------------- router 2: argmax over 2 logits of h2 flat (1250) ----------------
__global__ void k_d2(const float* __restrict__ h2, const float* __restrict__ w,
                     const float* __restrict__ bias, int* __restrict__ d2i,
                     float* __restrict__ outd2) {
  int b = blockIdx.x, t = threadIdx.x;
  const float* hb = h2 + b * 1250;
  float s0 = 0.f, s1 = 0.f;
  for (int i = t; i < 1250; i += 256) {
    float v = hb[i];
    s0 += v * w[i];
    s1 += v * w[1250 + i];
  }
#pragma unroll
  for (int off = 32; off >= 1; off >>= 1) {
    s0 += __shfl_down(s0, off);
    s1 += __shfl_down(s1, off);
  }
  __shared__ float red[4][2];
  if ((t & 63) == 0) { red[t >> 6][0] = s0; red[t >> 6][1] = s1; }
  __syncthreads();
  if (t == 0) {
    float l0 = bias[0] + red[0][0] + red[1][0] + red[2][0] + red[3][0];
    float l1v = bias[1] + red[0][1] + red[1][1] + red[2][1] + red[3][1];
    int idx = (l1v > l0) ? 1 : 0;
    d2i[b] = idx;
    outd2[b] = (float)idx;
  }
}

// ---------------- pool7 of h1 (top-left 7x7 window only, VALID) ----------------
__global__ void k_p7(const float* __restrict__ h1, float* __restrict__ p7) {
  int idx = blockIdx.x * 256 + threadIdx.x;
  if (idx >= BB * CC) return;
  int b = idx / CC, c = idx % CC;
  const float* hp = h1 + b * 8450 + c * 169;
  float m = -INFINITY;
#pragma unroll
  for (int y = 0; y < 7; y++)
#pragma unroll
    for (int x = 0; x < 7; x++) m = fmaxf(m, hp[y * 13 + x]);
  p7[idx] = m;
}

// ---------------- 50ch 3x3 conv (13x13 -> 11x11) + relu + pool2 -> [50,5,5] ----------------
// MODE 0: always (conv2 on h1 -> h2); MODE 1: only d1==1 (conv3 on c33 -> c3d)
template <int MODE>
__global__ __launch_bounds__(256) void k_conv5(const float* __restrict__ in,
                                               const float* __restrict__ w,
                                               const float* __restrict__ bias,
                                               const int* __restrict__ d1i,
                                               float* __restrict__ out) {
  int b = blockIdx.x;
  if (MODE == 1 && d1i[b] != 1) return;
  __shared__ float sh[8450];
  for (int i = threadIdx.x; i < 8450; i += 256) sh[i] = in[b * 8450 + i];
  __syncthreads();
  int t = threadIdx.x;
  if (t >= 250) return;
  int oc = t / 5, py = t % 5;
  float acc[5][4];
#pragma unroll
  for (int i = 0; i < 5; i++)
#pragma unroll
    for (int j = 0; j < 4; j++) acc[i][j] = 0.f;
  const float* wb = w + oc * 450;
  for (int ic = 0; ic < 50; ic++) {
    float wv[9];
#pragma unroll
    for (int i = 0; i < 9; i++) wv[i] = wb[ic * 9 + i];
    float r[4][13];
    const float* rp = sh + ic * 169 + 2 * py * 13;
#pragma unroll
    for (int rr = 0; rr < 4; rr++)
#pragma unroll
      for (int cx = 0; cx < 13; cx++) r[rr][cx] = rp[rr * 13 + cx];
#pragma unroll
    for (int px = 0; px < 5; px++)
#pragma unroll
      for (int dy = 0; dy < 2; dy++)
#pragma unroll
        for (int dx = 0; dx < 2; dx++) {
          float s = acc[px][dy * 2 + dx];
          int x0 = 2 * px + dx;
#pragma unroll
          for (int ky = 0; ky < 3; ky++)
#pragma unroll
            for (int kx = 0; kx < 3; kx++)
              s += r[dy + ky][x0 + kx] * wv[ky * 3 + kx];
          acc[px][dy * 2 + dx] = s;
        }
  }
  float bs = bias[oc];
#pragma unroll
  for (int px = 0; px < 5; px++) {
    float m = fmaxf(fmaxf(acc[px][0], acc[px][1]), fmaxf(acc[px][2], acc[px][3]));
    out[((b * 50 + oc) * 5 + py) * 5 + px] = fmaxf(m + bs, 0.f);
  }
}

// ---------------- c33 = Linear(13->13) on last dim of h1, IN PLACE, only d1==1 ----------------
__global__ void k_c33(float* __restrict__ h1, const float* __restrict__ w,
                      const float* __restrict__ bias, const int* __restrict__ d1i) {
  int idx = blockIdx.x * 256 + threadIdx.x;
  if (idx >= BB * CC * 13) return;
  int b = idx / (CC * 13);
  if (d1i[b] != 1) return;
  float* row = h1 + b * 8450 + (idx % (CC * 13)) * 13;
  float r[13];
#pragma unroll
  for (int k = 0; k < 13; k++) r[k] = row[k];
#pragma unroll
  for (int x = 0; x < 13; x++) {
    float s = bias[x];
    const float* wx = w + x * 13;
#pragma unroll
    for (int k = 0; k < 13; k++) s += r[k] * wx[k];
    row[x] = s;
  }
}

// ---------------- conv3 on h2 (5x5 -> 3x3) + relu + pool2 -> [50,1,1]; d1==0 && d2==0 ----------------
__global__ void k_c32k(const float* __restrict__ h2, const float* __restrict__ w,
                       const float* __restrict__ bias, const int* __restrict__ d1i,
                       const int* __restrict__ d2i, float* __restrict__ c32) {
  int idx = blockIdx.x * 256 + threadIdx.x;
  if (idx >= BB * CC) return;
  int b = idx / CC, oc = idx % CC;
  if (d1i[b] != 0 || d2i[b] != 0) return;
  const float* hb = h2 + b * 1250;
  const float* wb = w + oc * 450;
  float a[4] = {0.f, 0.f, 0.f, 0.f};
  for (int ic = 0; ic < 50; ic++) {
    float r[4][4];
#pragma unroll
    for (int y = 0; y < 4; y++)
#pragma unroll
      for (int x = 0; x < 4; x++) r[y][x] = hb[ic * 25 + y * 5 + x];
    float wv[9];
#pragma unroll
    for (int i = 0; i < 9; i++) wv[i] = wb[ic * 9 + i];
#pragma unroll
    for (int py = 0; py < 2; py++)
#pragma unroll
      for (int px = 0; px < 2; px++) {
        float s = a[py * 2 + px];
#pragma unroll
        for (int ky = 0; ky < 3; ky++)
#pragma unroll
          for (int kx = 0; kx < 3; kx++)
            s += r[py + ky][px + kx] * wv[ky * 3 + kx];
        a[py * 2 + px] = s;
      }
  }
  float m = fmaxf(fmaxf(a[0], a[1]), fmaxf(a[2], a[3]));
  c32[idx] = fmaxf(m + bias[oc], 0.f);
}

// ---------------- head: per (sample, 64-row slab) of the ACTIVE branch ----------------
// out row layout per sample: [0,500)=l11, [500,666)=l12, 666=c32, [667,692)=c3d
// Weight stream: per-wave LDS double-buffer (DS ops are wave-in-order, unlike SMEM
// whose OOO returns force lgkmcnt(0) drains). Each wave owns 128 j's (pack padded
// to 512 records, zero-records are exact no-ops), streamed in 32 batches of 4:
// coalesced global_load_dwordx4 -> ds_write_b128 -> uniform-address ds_read (broadcast).
__global__ __launch_bounds__(256) void k_head(
    const float* __restrict__ h2, const float* __restrict__ c3d,
    const float* __restrict__ c32, const float* __restrict__ p7,
    const int* __restrict__ d1i, const int* __restrict__ d2i,
    const float* __restrict__ pack, const float* __restrict__ l2b,
    const float* __restrict__ c1l1w, const float* __restrict__ c1l1b,
    const float* __restrict__ c2l1w, const float* __restrict__ c2l1b,
    float* __restrict__ out) {
  int b = blockIdx.x >> 3;
  int slab = blockIdx.x & 7;
  int d1 = d1i[b], d2 = d2i[b];
  int branch, nrows, rstart;
  if (d1 == 2)      { branch = 0; nrows = 500; rstart = 0; }
  else if (d1 == 1) { branch = 3; nrows = 25;  rstart = 667; }
  else if (d2 == 1) { branch = 1; nrows = 166; rstart = 500; }
  else              { branch = 2; nrows = 1;   rstart = 666; }
  int roff = slab * 64;
  if (roff >= nrows) return;
  int nr = nrows - roff; if (nr > 64) nr = 64;

  // smem serves two roles: V[64][51] during fill, then 4-wave x 2-buf x 4-rec x 64 wbuf
  __shared__ __align__(16) float smem[64 * 51];
  __shared__ float red[4][64][11];
  int t = threadIdx.x;

  for (int idx = t; idx < 64 * 50; idx += 256) {
    int row = idx / 50, col = idx % 50;
    if (row < nr) {
      int rr = roff + row;
      float val;
      if (branch == 0) {
        int c = rr / 10; int j = (rr % 10) * 50 + col;
        val = p7[b * 50 + c] * c1l1w[j] + c1l1b[j];
      } else if (branch == 1) {
        int k = rr * 50 + col; int c = k / 166, tt = k % 166;
        const float* hb = h2 + (b * 50 + c) * 25;
        float m = -INFINITY;
        for (int i = 0; i < 3; i++) {
          float a0 = hb[i * 5 + 0], a1 = hb[i * 5 + 1], a2 = hb[i * 5 + 2],
                a3 = hb[i * 5 + 3], a4 = hb[i * 5 + 4];
          for (int dj = 0; dj < 3; dj++) {
            int j = 3 * tt + dj;
            const float* wj = c2l1w + j * 5;
            float s = c2l1b[j] + a0 * wj[0] + a1 * wj[1] + a2 * wj[2] + a3 * wj[3] + a4 * wj[4];
            m = fmaxf(m, s);
          }
        }
        val = m;
      } else if (branch == 2) {
        val = c32[b * 50 + col];
      } else {
        int k = rr * 50 + col; int c = k / 25, s5 = k % 25;
        val = c3d[(b * 50 + c) * 25 + s5];
      }
      smem[row * 51 + col] = val;
    }
  }
  __syncthreads();

  int row = t & 63;
  int chunk = t >> 6;
  int lane = t & 63;
  float v[50];
#pragma unroll
  for (int i = 0; i < 50; i++) v[i] = smem[row * 51 + i];
  __syncthreads();   // everyone done reading V; smem becomes wbuf

  float* wbuf = smem + chunk * 512;           // per-wave: 2 bufs x 256 floats
  const float* gsrc = pack + chunk * 128 * 64 + lane * 4;

  float part[10];
#pragma unroll
  for (int k = 0; k < 10; k++) part[k] = 0.f;

  float4 stage = *(const float4*)gsrc;        // batch 0
  *(float4*)(wbuf + lane * 4) = stage;        // -> buf 0
  for (int bt = 0; bt < 32; bt++) {
    int cur = bt & 1;
    if (bt + 1 < 32) stage = *(const float4*)(gsrc + (bt + 1) * 256);
    const float* bb = wbuf + cur * 256;
#pragma unroll
    for (int r = 0; r < 4; r++) {
      const float* rec = bb + r * 64;
      float h0 = 0.f, h1 = 0.f, h2s = 0.f, h3 = 0.f;
#pragma unroll
      for (int i = 0; i < 48; i += 4) {
        h0 += v[i + 0] * rec[i + 0];
        h1 += v[i + 1] * rec[i + 1];
        h2s += v[i + 2] * rec[i + 2];
        h3 += v[i + 3] * rec[i + 3];
      }
      h0 += v[48] * rec[48];
      h1 += v[49] * rec[49];
      float h = ((h0 + h2s) + (h1 + h3)) + rec[50];
      h = fmaxf(h, 0.f);
#pragma unroll
      for (int k = 0; k < 10; k++) part[k] += h * rec[51 + k];
    }
    if (bt + 1 < 32) *(float4*)(wbuf + (1 - cur) * 256 + lane * 4) = stage;
  }
#pragma unroll
  for (int k = 0; k < 10; k++) red[chunk][row][k] = part[k];
  __syncthreads();

  if (t < 64 && t < nr) {
    float o[10];
    float m = -INFINITY;
#pragma unroll
    for (int k = 0; k < 10; k++) {
      o[k] = red[0][t][k] + red[1][t][k] + red[2][t][k] + red[3][t][k] + l2b[k];
      m = fmaxf(m, o[k]);
    }
    float s = 0.f;
#pragma unroll
    for (int k = 0; k < 10; k++) s += expf(o[k] - m);
    float lse = m + logf(s);
    float* orow = out + (b * 692 + rstart + roff + t) * 10;
#pragma unroll
    for (int k = 0; k < 10; k++) orow[k] = o[k] - lse;
  }
}

extern "C" void kernel_launch(void* const* d_in, const int* in_sizes, int n_in,
                              void* d_out, int out_size, void* d_ws, size_t ws_size,
                              hipStream_t stream) {
  const float* x     = (const float*)d_in[0];
  const float* c1w   = (const float*)d_in[1];
  const float* c1b   = (const float*)d_in[2];
  const float* c2w   = (const float*)d_in[3];
  const float* c2b   = (const float*)d_in[4];
  const float* c3w   = (const float*)d_in[5];
  const float* c3b   = (const float*)d_in[6];
  const float* l1w   = (const float*)d_in[7];
  const float* l1b   = (const float*)d_in[8];
  const float* l2w   = (const float*)d_in[9];
  const float* l2b   = (const float*)d_in[10];
  const float* d1w   = (const float*)d_in[11];
  const float* d1b   = (const float*)d_in[12];
  const float* d2w   = (const float*)d_in[13];
  const float* d2b   = (const float*)d_in[14];
  const float* c13w  = (const float*)d_in[15];
  const float* c13b  = (const float*)d_in[16];
  const float* c1l1w = (const float*)d_in[17];
  const float* c1l1b = (const float*)d_in[18];
  const float* c2l1w = (const float*)d_in[19];
  const float* c2l1b = (const float*)d_in[20];
  float* out = (float*)d_out;

  float* ws  = (float*)d_ws;
  float* h1  = ws;                 // 4,326,400 floats
  float* h2  = h1 + 4326400;       // 640,000
  float* c3d = h2 + 640000;        // 640,000
  float* c32 = c3d + 640000;       // 25,600
  float* p7  = c32 + 25600;        // 25,600
  int*   d1i = (int*)(p7 + 25600); // 512
  int*   d2i = d1i + 512;          // 512
  float* pack = (float*)(d2i + 512); // 32,768 floats (512 x 64)

  float* outd1 = out + 512 * 692 * 10;        // 3,542,040
  float* outd2 = outd1 + 512;

  k_zero<<<3460, 256, 0, stream>>>(out, 885510);                 // 3,542,040/4
  k_pack<<<128, 256, 0, stream>>>(l1w, l1b, l2w, pack);
  k_conv1<<<16900, 256, 0, stream>>>(x, c1w, c1b, h1);
  k_d1<<<512, 256, 0, stream>>>(h1, d1w, d1b, d1i, outd1);
  k_p7<<<100, 256, 0, stream>>>(h1, p7);
  k_conv5<0><<<512, 256, 0, stream>>>(h1, c2w, c2b, d1i, h2);    // conv2 -> h2 (all samples)
  k_d2<<<512, 256, 0, stream>>>(h2, d2w, d2b, d2i, outd2);
  k_c33<<<1300, 256, 0, stream>>>(h1, c13w, c13b, d1i);          // in-place lin13 (d1==1)
  k_conv5<1><<<512, 256, 0, stream>>>(h1, c3w, c3b, d1i, c3d);   // conv3 on c33 (d1==1)
  k_c32k<<<100, 256, 0, stream>>>(h2, c3w, c3b, d1i, d2i, c32);  // conv3 on h2 (d1==0,d2==0)
  k_head<<<4096, 256, 0, stream>>>(h2, c3d, c32, p7, d1i, d2i,
                                   pack, l2b, c1l1w, c1l1b,
                                   c2l1w, c2l1b, out);
}

// Round 6
// 359.589 us; speedup vs baseline: 1.3973x; 1.3973x over previous
//
#include <hip/hip_runtime.h>
#include <hip/hip_bf16.h>
#include <math.h>

#define BB 512
#define CC 50

typedef __attribute__((ext_vector_type(8))) __bf16 bf16x8;
typedef __attribute__((ext_vector_type(4))) float f32x4;

// ---------------- zero-fill out[0 : 512*692*10) ----------------
__global__ void k_zero(float* __restrict__ out, int n4) {
  int i = blockIdx.x * 256 + threadIdx.x;
  if (i < n4) {
    float4 z = {0.f, 0.f, 0.f, 0.f};
    ((float4*)out)[i] = z;
  }
}

// ---------------- pack head weights to bf16 fragments ----------------
// W1p[512 j][64 k]: k<50 = l1w[j][k], k==50 = l1b[j] (bias as K-row), else 0; j>=500 all 0.
// W2p[16 n][512 k2]: n<10 && k2<500 = l2w[n][k2], else 0.
__global__ void k_pack(const float* __restrict__ l1w, const float* __restrict__ l1b,
                       const float* __restrict__ l2w,
                       __bf16* __restrict__ W1p, __bf16* __restrict__ W2p) {
  int idx = blockIdx.x * 256 + threadIdx.x;
  if (idx < 512 * 64) {
    int j = idx >> 6, k = idx & 63;
    float v = 0.f;
    if (j < 500) {
      if (k < 50) v = l1w[j * 50 + k];
      else if (k == 50) v = l1b[j];
    }
    W1p[idx] = (__bf16)v;
  } else if (idx < 512 * 64 + 16 * 512) {
    int i2 = idx - 512 * 64;
    int n = i2 >> 9, k2 = i2 & 511;
    float v = (n < 10 && k2 < 500) ? l2w[n * 500 + k2] : 0.f;
    W2p[i2] = (__bf16)v;
  }
}

// ---------------- conv1 (1->50, 3x3) + relu + pool2 -> h1[512,50,13,13] ----------------
__global__ void k_conv1(const float* __restrict__ x, const float* __restrict__ w,
                        const float* __restrict__ bias, float* __restrict__ h1) {
  int idx = blockIdx.x * 256 + threadIdx.x;
  if (idx >= BB * CC * 169) return;
  int b = idx / (CC * 169);
  int rem = idx % (CC * 169);
  int c = rem / 169;
  int p = rem % 169;
  int py = p / 13, px = p % 13;
  const float* xi = x + b * 784;
  float wr[9];
#pragma unroll
  for (int i = 0; i < 9; i++) wr[i] = w[c * 9 + i];
  float m = -INFINITY;
#pragma unroll
  for (int dy = 0; dy < 2; dy++)
#pragma unroll
    for (int dx = 0; dx < 2; dx++) {
      int y0 = 2 * py + dy, x0 = 2 * px + dx;
      float s = 0.f;
#pragma unroll
      for (int ky = 0; ky < 3; ky++)
#pragma unroll
        for (int kx = 0; kx < 3; kx++)
          s += xi[(y0 + ky) * 28 + x0 + kx] * wr[ky * 3 + kx];
      m = fmaxf(m, s);
    }
  h1[idx] = fmaxf(m + bias[c], 0.f);
}

// ---------------- router 1: argmax over 3 logits of h1 flat (8450) ----------------
__global__ void k_d1(const float* __restrict__ h1, const float* __restrict__ w,
                     const float* __restrict__ bias, int* __restrict__ d1i,
                     float* __restrict__ outd1) {
  int b = blockIdx.x, t = threadIdx.x;
  const float* hb = h1 + b * 8450;
  float s0 = 0.f, s1 = 0.f, s2 = 0.f;
  for (int i = t; i < 8450; i += 256) {
    float v = hb[i];
    s0 += v * w[i];
    s1 += v * w[8450 + i];
    s2 += v * w[16900 + i];
  }
#pragma unroll
  for (int off = 32; off >= 1; off >>= 1) {
    s0 += __shfl_down(s0, off);
    s1 += __shfl_down(s1, off);
    s2 += __shfl_down(s2, off);
  }
  __shared__ float red[4][3];
  if ((t & 63) == 0) { red[t >> 6][0] = s0; red[t >> 6][1] = s1; red[t >> 6][2] = s2; }
  __syncthreads();
  if (t == 0) {
    float l0 = bias[0], l1v = bias[1], l2v = bias[2];
    for (int wv = 0; wv < 4; wv++) { l0 += red[wv][0]; l1v += red[wv][1]; l2v += red[wv][2]; }
    int idx = 0; float best = l0;
    if (l1v > best) { best = l1v; idx = 1; }
    if (l2v > best) { best = l2v; idx = 2; }
    d1i[b] = idx;
    outd1[b] = (float)idx;
  }
}

// ---------------- router 2: argmax over 2 logits of h2 flat (1250) ----------------
__global__ void k_d2(const float* __restrict__ h2, const float* __restrict__ w,
                     const float* __restrict__ bias, int* __restrict__ d2i,
                     float* __restrict__ outd2) {
  int b = blockIdx.x, t = threadIdx.x;
  const float* hb = h2 + b * 1250;
  float s0 = 0.f, s1 = 0.f;
  for (int i = t; i < 1250; i += 256) {
    float v = hb[i];
    s0 += v * w[i];
    s1 += v * w[1250 + i];
  }
#pragma unroll
  for (int off = 32; off >= 1; off >>= 1) {
    s0 += __shfl_down(s0, off);
    s1 += __shfl_down(s1, off);
  }
  __shared__ float red[4][2];
  if ((t & 63) == 0) { red[t >> 6][0] = s0; red[t >> 6][1] = s1; }
  __syncthreads();
  if (t == 0) {
    float l0 = bias[0] + red[0][0] + red[1][0] + red[2][0] + red[3][0];
    float l1v = bias[1] + red[0][1] + red[1][1] + red[2][1] + red[3][1];
    int idx = (l1v > l0) ? 1 : 0;
    d2i[b] = idx;
    outd2[b] = (float)idx;
  }
}

// ---------------- pool7 of h1 (top-left 7x7 window only, VALID) ----------------
__global__ void k_p7(const float* __restrict__ h1, float* __restrict__ p7) {
  int idx = blockIdx.x * 256 + threadIdx.x;
  if (idx >= BB * CC) return;
  int b = idx / CC, c = idx % CC;
  const float* hp = h1 + b * 8450 + c * 169;
  float m = -INFINITY;
#pragma unroll
  for (int y = 0; y < 7; y++)
#pragma unroll
    for (int x = 0; x < 7; x++) m = fmaxf(m, hp[y * 13 + x]);
  p7[idx] = m;
}

// ---------------- 50ch 3x3 conv (13x13 -> 11x11) + relu + pool2 -> [50,5,5] ----------------
template <int MODE>
__global__ __launch_bounds__(256) void k_conv5(const float* __restrict__ in,
                                               const float* __restrict__ w,
                                               const float* __restrict__ bias,
                                               const int* __restrict__ d1i,
                                               float* __restrict__ out) {
  int b = blockIdx.x;
  if (MODE == 1 && d1i[b] != 1) return;
  __shared__ float sh[8450];
  for (int i = threadIdx.x; i < 8450; i += 256) sh[i] = in[b * 8450 + i];
  __syncthreads();
  int t = threadIdx.x;
  if (t >= 250) return;
  int oc = t / 5, py = t % 5;
  float acc[5][4];
#pragma unroll
  for (int i = 0; i < 5; i++)
#pragma unroll
    for (int j = 0; j < 4; j++) acc[i][j] = 0.f;
  const float* wb = w + oc * 450;
  for (int ic = 0; ic < 50; ic++) {
    float wv[9];
#pragma unroll
    for (int i = 0; i < 9; i++) wv[i] = wb[ic * 9 + i];
    float r[4][13];
    const float* rp = sh + ic * 169 + 2 * py * 13;
#pragma unroll
    for (int rr = 0; rr < 4; rr++)
#pragma unroll
      for (int cx = 0; cx < 13; cx++) r[rr][cx] = rp[rr * 13 + cx];
#pragma unroll
    for (int px = 0; px < 5; px++)
#pragma unroll
      for (int dy = 0; dy < 2; dy++)
#pragma unroll
        for (int dx = 0; dx < 2; dx++) {
          float s = acc[px][dy * 2 + dx];
          int x0 = 2 * px + dx;
#pragma unroll
          for (int ky = 0; ky < 3; ky++)
#pragma unroll
            for (int kx = 0; kx < 3; kx++)
              s += r[dy + ky][x0 + kx] * wv[ky * 3 + kx];
          acc[px][dy * 2 + dx] = s;
        }
  }
  float bs = bias[oc];
#pragma unroll
  for (int px = 0; px < 5; px++) {
    float m = fmaxf(fmaxf(acc[px][0], acc[px][1]), fmaxf(acc[px][2], acc[px][3]));
    out[((b * 50 + oc) * 5 + py) * 5 + px] = fmaxf(m + bs, 0.f);
  }
}

// ---------------- c33 = Linear(13->13) on last dim of h1, IN PLACE, only d1==1 ----------------
__global__ void k_c33(float* __restrict__ h1, const float* __restrict__ w,
                      const float* __restrict__ bias, const int* __restrict__ d1i) {
  int idx = blockIdx.x * 256 + threadIdx.x;
  if (idx >= BB * CC * 13) return;
  int b = idx / (CC * 13);
  if (d1i[b] != 1) return;
  float* row = h1 + b * 8450 + (idx % (CC * 13)) * 13;
  float r[13];
#pragma unroll
  for (int k = 0; k < 13; k++) r[k] = row[k];
#pragma unroll
  for (int x = 0; x < 13; x++) {
    float s = bias[x];
    const float* wx = w + x * 13;
#pragma unroll
    for (int k = 0; k < 13; k++) s += r[k] * wx[k];
    row[x] = s;
  }
}

// ---------------- conv3 on h2 (5x5 -> 3x3) + relu + pool2 -> [50,1,1]; d1==0 && d2==0 ----------------
__global__ void k_c32k(const float* __restrict__ h2, const float* __restrict__ w,
                       const float* __restrict__ bias, const int* __restrict__ d1i,
                       const int* __restrict__ d2i, float* __restrict__ c32) {
  int idx = blockIdx.x * 256 + threadIdx.x;
  if (idx >= BB * CC) return;
  int b = idx / CC, oc = idx % CC;
  if (d1i[b] != 0 || d2i[b] != 0) return;
  const float* hb = h2 + b * 1250;
  const float* wb = w + oc * 450;
  float a[4] = {0.f, 0.f, 0.f, 0.f};
  for (int ic = 0; ic < 50; ic++) {
    float r[4][4];
#pragma unroll
    for (int y = 0; y < 4; y++)
#pragma unroll
      for (int x = 0; x < 4; x++) r[y][x] = hb[ic * 25 + y * 5 + x];
    float wv[9];
#pragma unroll
    for (int i = 0; i < 9; i++) wv[i] = wb[ic * 9 + i];
#pragma unroll
    for (int py = 0; py < 2; py++)
#pragma unroll
      for (int px = 0; px < 2; px++) {
        float s = a[py * 2 + px];
#pragma unroll
        for (int ky = 0; ky < 3; ky++)
#pragma unroll
          for (int kx = 0; kx < 3; kx++)
            s += r[py + ky][px + kx] * wv[ky * 3 + kx];
        a[py * 2 + px] = s;
      }
  }
  float m = fmaxf(fmaxf(a[0], a[1]), fmaxf(a[2], a[3]));
  c32[idx] = fmaxf(m + bias[oc], 0.f);
}

// ---------------- head (MFMA): per (sample, 64-row slab) of the ACTIVE branch ----------------
// GEMM1: V[64x64] @ W1p^T -> H[64x512] (bias folded as V col 50 = 1.0), relu, bf16.
// Wave w owns M-tile w (16 rows) end-to-end: A1-frags built once from LDS; B1-frags
// streamed from global bf16 with distance-1 prefetch (counted vmcnt works on VMEM).
// GEMM2: relu(H)[16x512] @ W2p^T -> logits[16x10], H transposed through a per-wave
// 16x32 LDS tile (D layout: col=lane&15,row=(lane>>4)*4+reg; A layout: row=lane&15,
// k=(lane>>4)*8..+8). No cross-wave barriers after the V fill.
__global__ __launch_bounds__(256) void k_head(
    const float* __restrict__ h2, const float* __restrict__ c3d,
    const float* __restrict__ c32, const float* __restrict__ p7,
    const int* __restrict__ d1i, const int* __restrict__ d2i,
    const __bf16* __restrict__ W1p, const __bf16* __restrict__ W2p,
    const float* __restrict__ l2b,
    const float* __restrict__ c1l1w, const float* __restrict__ c1l1b,
    const float* __restrict__ c2l1w, const float* __restrict__ c2l1b,
    float* __restrict__ out) {
  int b = blockIdx.x >> 3;
  int slab = blockIdx.x & 7;
  int d1 = d1i[b], d2 = d2i[b];
  int branch, nrows, rstart;
  if (d1 == 2)      { branch = 0; nrows = 500; rstart = 0; }
  else if (d1 == 1) { branch = 3; nrows = 25;  rstart = 667; }
  else if (d2 == 1) { branch = 1; nrows = 166; rstart = 500; }
  else              { branch = 2; nrows = 1;   rstart = 666; }
  int roff = slab * 64;
  if (roff >= nrows) return;
  int nr = nrows - roff; if (nr > 64) nr = 64;

  __shared__ __align__(16) float Vs[64 * 66];        // [row][k], k: 0..49=v, 50=1.0, 51..65=0
  __shared__ __align__(16) __bf16 Ht[4][16 * 40];    // per-wave H transpose tile [16r][32j] stride 40
  __shared__ float Lsm[64 * 12];
  int t = threadIdx.x;

  for (int idx = t; idx < 64 * 66; idx += 256) {
    int row = idx / 66, col = idx % 66;
    float val = 0.f;
    if (col == 50) val = 1.0f;
    else if (col < 50 && row < nr) {
      int rr = roff + row;
      if (branch == 0) {
        int c = rr / 10; int j = (rr % 10) * 50 + col;
        val = p7[b * 50 + c] * c1l1w[j] + c1l1b[j];
      } else if (branch == 1) {
        int k = rr * 50 + col; int c = k / 166, tt = k % 166;
        const float* hb = h2 + (b * 50 + c) * 25;
        float m = -INFINITY;
        for (int i = 0; i < 3; i++) {
          float a0 = hb[i * 5 + 0], a1 = hb[i * 5 + 1], a2 = hb[i * 5 + 2],
                a3 = hb[i * 5 + 3], a4 = hb[i * 5 + 4];
          for (int dj = 0; dj < 3; dj++) {
            int j = 3 * tt + dj;
            const float* wj = c2l1w + j * 5;
            float s = c2l1b[j] + a0 * wj[0] + a1 * wj[1] + a2 * wj[2] + a3 * wj[3] + a4 * wj[4];
            m = fmaxf(m, s);
          }
        }
        val = m;
      } else if (branch == 2) {
        val = c32[b * 50 + col];
      } else {
        int k = rr * 50 + col; int c = k / 25, s5 = k % 25;
        val = c3d[(b * 50 + c) * 25 + s5];
      }
    }
    Vs[idx] = val;
  }
  __syncthreads();

  int wv = t >> 6, lane = t & 63;
  int lr = lane & 15, lg = lane >> 4;

  // A1 fragments (once per wave): lane holds row (wv*16+lr), k = ks*32 + lg*8 .. +8
  bf16x8 a1[2];
#pragma unroll
  for (int ks = 0; ks < 2; ++ks) {
    const float* vp = Vs + (wv * 16 + lr) * 66 + ks * 32 + lg * 8;
    bf16x8 a;
#pragma unroll
    for (int i = 0; i < 8; ++i) a[i] = (__bf16)vp[i];
    a1[ks] = a;
  }

  __bf16* ht = Ht[wv];
  const __bf16* w1base = W1p + lr * 64 + lg * 8;    // + jt*1024 + ks*32
  const __bf16* w2base = W2p + lr * 512 + lg * 8;   // + q*32

  f32x4 acc2 = {0.f, 0.f, 0.f, 0.f};
  bf16x8 nb0 = *(const bf16x8*)(w1base);
  bf16x8 nb1 = *(const bf16x8*)(w1base + 32);
  bf16x8 b2n = *(const bf16x8*)(w2base);

  for (int jt = 0; jt < 32; ++jt) {
    bf16x8 b0 = nb0, b1 = nb1;
    if (jt + 1 < 32) {
      const __bf16* p = w1base + (jt + 1) * 1024;
      nb0 = *(const bf16x8*)p;
      nb1 = *(const bf16x8*)(p + 32);
    }
    f32x4 d = {0.f, 0.f, 0.f, 0.f};
    d = __builtin_amdgcn_mfma_f32_16x16x32_bf16(a1[0], b0, d, 0, 0, 0);
    d = __builtin_amdgcn_mfma_f32_16x16x32_bf16(a1[1], b1, d, 0, 0, 0);
    int p16 = (jt & 1) << 4;
#pragma unroll
    for (int r = 0; r < 4; ++r)
      ht[(lg * 4 + r) * 40 + p16 + lr] = (__bf16)fmaxf(d[r], 0.f);
    if (jt & 1) {
      int q = jt >> 1;
      bf16x8 a2 = *(const bf16x8*)(ht + lr * 40 + lg * 8);
      bf16x8 bb2 = b2n;
      if (q + 1 < 16) b2n = *(const bf16x8*)(w2base + (q + 1) * 32);
      acc2 = __builtin_amdgcn_mfma_f32_16x16x32_bf16(a2, bb2, acc2, 0, 0, 0);
    }
  }

  // logits: lane holds n = lr, local rows lg*4 + r
  if (lr < 10) {
#pragma unroll
    for (int r = 0; r < 4; ++r) Lsm[(wv * 16 + lg * 4 + r) * 12 + lr] = acc2[r];
  }
  // per-wave softmax (same-wave LDS ordering; no barrier needed)
  if (lane < 16) {
    int rl = wv * 16 + lane;
    if (rl < nr) {
      float o[10];
      float m = -INFINITY;
#pragma unroll
      for (int k = 0; k < 10; ++k) { o[k] = Lsm[rl * 12 + k] + l2b[k]; m = fmaxf(m, o[k]); }
      float s = 0.f;
#pragma unroll
      for (int k = 0; k < 10; ++k) s += expf(o[k] - m);
      float lse = m + logf(s);
      float* orow = out + (b * 692 + rstart + roff + rl) * 10;
#pragma unroll
      for (int k = 0; k < 10; ++k) orow[k] = o[k] - lse;
    }
  }
}

extern "C" void kernel_launch(void* const* d_in, const int* in_sizes, int n_in,
                              void* d_out, int out_size, void* d_ws, size_t ws_size,
                              hipStream_t stream) {
  const float* x     = (const float*)d_in[0];
  const float* c1w   = (const float*)d_in[1];
  const float* c1b   = (const float*)d_in[2];
  const float* c2w   = (const float*)d_in[3];
  const float* c2b   = (const float*)d_in[4];
  const float* c3w   = (const float*)d_in[5];
  const float* c3b   = (const float*)d_in[6];
  const float* l1w   = (const float*)d_in[7];
  const float* l1b   = (const float*)d_in[8];
  const float* l2w   = (const float*)d_in[9];
  const float* l2b   = (const float*)d_in[10];
  const float* d1w   = (const float*)d_in[11];
  const float* d1b   = (const float*)d_in[12];
  const float* d2w   = (const float*)d_in[13];
  const float* d2b   = (const float*)d_in[14];
  const float* c13w  = (const float*)d_in[15];
  const float* c13b  = (const float*)d_in[16];
  const float* c1l1w = (const float*)d_in[17];
  const float* c1l1b = (const float*)d_in[18];
  const float* c2l1w = (const float*)d_in[19];
  const float* c2l1b = (const float*)d_in[20];
  float* out = (float*)d_out;

  float* ws  = (float*)d_ws;
  float* h1  = ws;                 // 4,326,400 floats
  float* h2  = h1 + 4326400;       // 640,000
  float* c3d = h2 + 640000;        // 640,000
  float* c32 = c3d + 640000;       // 25,600
  float* p7  = c32 + 25600;        // 25,600
  int*   d1i = (int*)(p7 + 25600); // 512
  int*   d2i = d1i + 512;          // 512
  __bf16* W1p = (__bf16*)(d2i + 512);   // 512*64 bf16
  __bf16* W2p = W1p + 512 * 64;         // 16*512 bf16

  float* outd1 = out + 512 * 692 * 10;
  float* outd2 = outd1 + 512;

  k_zero<<<3460, 256, 0, stream>>>(out, 885510);
  k_pack<<<160, 256, 0, stream>>>(l1w, l1b, l2w, W1p, W2p);
  k_conv1<<<16900, 256, 0, stream>>>(x, c1w, c1b, h1);
  k_d1<<<512, 256, 0, stream>>>(h1, d1w, d1b, d1i, outd1);
  k_p7<<<100, 256, 0, stream>>>(h1, p7);
  k_conv5<0><<<512, 256, 0, stream>>>(h1, c2w, c2b, d1i, h2);
  k_d2<<<512, 256, 0, stream>>>(h2, d2w, d2b, d2i, outd2);
  k_c33<<<1300, 256, 0, stream>>>(h1, c13w, c13b, d1i);
  k_conv5<1><<<512, 256, 0, stream>>>(h1, c3w, c3b, d1i, c3d);
  k_c32k<<<100, 256, 0, stream>>>(h2, c3w, c3b, d1i, d2i, c32);
  k_head<<<4096, 256, 0, stream>>>(h2, c3d, c32, p7, d1i, d2i,
                                   W1p, W2p, l2b, c1l1w, c1l1b,
                                   c2l1w, c2l1b, out);
}

// Round 7
// 271.593 us; speedup vs baseline: 1.8500x; 1.3240x over previous
//
#include <hip/hip_runtime.h>
#include <hip/hip_bf16.h>
#include <math.h>

#define BB 512
#define CC 50

typedef __attribute__((ext_vector_type(8))) __bf16 bf16x8;
typedef __attribute__((ext_vector_type(4))) float f32x4;

// ---------------- zero-fill out[0 : 512*692*10) ----------------
__global__ void k_zero(float* __restrict__ out, int n4) {
  int i = blockIdx.x * 256 + threadIdx.x;
  if (i < n4) {
    float4 z = {0.f, 0.f, 0.f, 0.f};
    ((float4*)out)[i] = z;
  }
}

// ---------------- pack head weights to bf16 fragments ----------------
// W1p[512 j][64 k]: k<50 = l1w[j][k], k==50 = l1b[j] (bias as K-row), else 0; j>=500 all 0.
// W2p[16 n][512 k2]: n<10 && k2<500 = l2w[n][k2], else 0.
__global__ void k_pack(const float* __restrict__ l1w, const float* __restrict__ l1b,
                       const float* __restrict__ l2w,
                       __bf16* __restrict__ W1p, __bf16* __restrict__ W2p) {
  int idx = blockIdx.x * 256 + threadIdx.x;
  if (idx < 512 * 64) {
    int j = idx >> 6, k = idx & 63;
    float v = 0.f;
    if (j < 500) {
      if (k < 50) v = l1w[j * 50 + k];
      else if (k == 50) v = l1b[j];
    }
    W1p[idx] = (__bf16)v;
  } else if (idx < 512 * 64 + 16 * 512) {
    int i2 = idx - 512 * 64;
    int n = i2 >> 9, k2 = i2 & 511;
    float v = (n < 10 && k2 < 500) ? l2w[n * 500 + k2] : 0.f;
    W2p[i2] = (__bf16)v;
  }
}

// ---------------- conv1 (1->50, 3x3) + relu + pool2 -> h1[512,50,13,13] ----------------
__global__ void k_conv1(const float* __restrict__ x, const float* __restrict__ w,
                        const float* __restrict__ bias, float* __restrict__ h1) {
  int idx = blockIdx.x * 256 + threadIdx.x;
  if (idx >= BB * CC * 169) return;
  int b = idx / (CC * 169);
  int rem = idx % (CC * 169);
  int c = rem / 169;
  int p = rem % 169;
  int py = p / 13, px = p % 13;
  const float* xi = x + b * 784;
  float wr[9];
#pragma unroll
  for (int i = 0; i < 9; i++) wr[i] = w[c * 9 + i];
  float m = -INFINITY;
#pragma unroll
  for (int dy = 0; dy < 2; dy++)
#pragma unroll
    for (int dx = 0; dx < 2; dx++) {
      int y0 = 2 * py + dy, x0 = 2 * px + dx;
      float s = 0.f;
#pragma unroll
      for (int ky = 0; ky < 3; ky++)
#pragma unroll
        for (int kx = 0; kx < 3; kx++)
          s += xi[(y0 + ky) * 28 + x0 + kx] * wr[ky * 3 + kx];
      m = fmaxf(m, s);
    }
  h1[idx] = fmaxf(m + bias[c], 0.f);
}

// ---------------- router 1: argmax over 3 logits of h1 flat (8450) ----------------
__global__ void k_d1(const float* __restrict__ h1, const float* __restrict__ w,
                     const float* __restrict__ bias, int* __restrict__ d1i,
                     float* __restrict__ outd1) {
  int b = blockIdx.x, t = threadIdx.x;
  const float* hb = h1 + b * 8450;
  float s0 = 0.f, s1 = 0.f, s2 = 0.f;
  for (int i = t; i < 8450; i += 256) {
    float v = hb[i];
    s0 += v * w[i];
    s1 += v * w[8450 + i];
    s2 += v * w[16900 + i];
  }
#pragma unroll
  for (int off = 32; off >= 1; off >>= 1) {
    s0 += __shfl_down(s0, off);
    s1 += __shfl_down(s1, off);
    s2 += __shfl_down(s2, off);
  }
  __shared__ float red[4][3];
  if ((t & 63) == 0) { red[t >> 6][0] = s0; red[t >> 6][1] = s1; red[t >> 6][2] = s2; }
  __syncthreads();
  if (t == 0) {
    float l0 = bias[0], l1v = bias[1], l2v = bias[2];
    for (int wv = 0; wv < 4; wv++) { l0 += red[wv][0]; l1v += red[wv][1]; l2v += red[wv][2]; }
    int idx = 0; float best = l0;
    if (l1v > best) { best = l1v; idx = 1; }
    if (l2v > best) { best = l2v; idx = 2; }
    d1i[b] = idx;
    outd1[b] = (float)idx;
  }
}

// ---------------- router 2: argmax over 2 logits of h2 flat (1250) ----------------
__global__ void k_d2(const float* __restrict__ h2, const float* __restrict__ w,
                     const float* __restrict__ bias, int* __restrict__ d2i,
                     float* __restrict__ outd2) {
  int b = blockIdx.x, t = threadIdx.x;
  const float* hb = h2 + b * 1250;
  float s0 = 0.f, s1 = 0.f;
  for (int i = t; i < 1250; i += 256) {
    float v = hb[i];
    s0 += v * w[i];
    s1 += v * w[1250 + i];
  }
#pragma unroll
  for (int off = 32; off >= 1; off >>= 1) {
    s0 += __shfl_down(s0, off);
    s1 += __shfl_down(s1, off);
  }
  __shared__ float red[4][2];
  if ((t & 63) == 0) { red[t >> 6][0] = s0; red[t >> 6][1] = s1; }
  __syncthreads();
  if (t == 0) {
    float l0 = bias[0] + red[0][0] + red[1][0] + red[2][0] + red[3][0];
    float l1v = bias[1] + red[0][1] + red[1][1] + red[2][1] + red[3][1];
    int idx = (l1v > l0) ? 1 : 0;
    d2i[b] = idx;
    outd2[b] = (float)idx;
  }
}

// ---------------- pool7 of h1 (top-left 7x7 window only, VALID) ----------------
__global__ void k_p7(const float* __restrict__ h1, float* __restrict__ p7) {
  int idx = blockIdx.x * 256 + threadIdx.x;
  if (idx >= BB * CC) return;
  int b = idx / CC, c = idx % CC;
  const float* hp = h1 + b * 8450 + c * 169;
  float m = -INFINITY;
#pragma unroll
  for (int y = 0; y < 7; y++)
#pragma unroll
    for (int x = 0; x < 7; x++) m = fmaxf(m, hp[y * 13 + x]);
  p7[idx] = m;
}

// ---------------- 50ch 3x3 conv (13x13 -> 11x11) + relu + pool2 -> [50,5,5] ----------------
template <int MODE>
__global__ __launch_bounds__(256) void k_conv5(const float* __restrict__ in,
                                               const float* __restrict__ w,
                                               const float* __restrict__ bias,
                                               const int* __restrict__ d1i,
                                               float* __restrict__ out) {
  int b = blockIdx.x;
  if (MODE == 1 && d1i[b] != 1) return;
  __shared__ float sh[8450];
  for (int i = threadIdx.x; i < 8450; i += 256) sh[i] = in[b * 8450 + i];
  __syncthreads();
  int t = threadIdx.x;
  if (t >= 250) return;
  int oc = t / 5, py = t % 5;
  float acc[5][4];
#pragma unroll
  for (int i = 0; i < 5; i++)
#pragma unroll
    for (int j = 0; j < 4; j++) acc[i][j] = 0.f;
  const float* wb = w + oc * 450;
  for (int ic = 0; ic < 50; ic++) {
    float wv[9];
#pragma unroll
    for (int i = 0; i < 9; i++) wv[i] = wb[ic * 9 + i];
    float r[4][13];
    const float* rp = sh + ic * 169 + 2 * py * 13;
#pragma unroll
    for (int rr = 0; rr < 4; rr++)
#pragma unroll
      for (int cx = 0; cx < 13; cx++) r[rr][cx] = rp[rr * 13 + cx];
#pragma unroll
    for (int px = 0; px < 5; px++)
#pragma unroll
      for (int dy = 0; dy < 2; dy++)
#pragma unroll
        for (int dx = 0; dx < 2; dx++) {
          float s = acc[px][dy * 2 + dx];
          int x0 = 2 * px + dx;
#pragma unroll
          for (int ky = 0; ky < 3; ky++)
#pragma unroll
            for (int kx = 0; kx < 3; kx++)
              s += r[dy + ky][x0 + kx] * wv[ky * 3 + kx];
          acc[px][dy * 2 + dx] = s;
        }
  }
  float bs = bias[oc];
#pragma unroll
  for (int px = 0; px < 5; px++) {
    float m = fmaxf(fmaxf(acc[px][0], acc[px][1]), fmaxf(acc[px][2], acc[px][3]));
    out[((b * 50 + oc) * 5 + py) * 5 + px] = fmaxf(m + bs, 0.f);
  }
}

// ---------------- c33 = Linear(13->13) on last dim of h1, IN PLACE, only d1==1 ----------------
__global__ void k_c33(float* __restrict__ h1, const float* __restrict__ w,
                      const float* __restrict__ bias, const int* __restrict__ d1i) {
  int idx = blockIdx.x * 256 + threadIdx.x;
  if (idx >= BB * CC * 13) return;
  int b = idx / (CC * 13);
  if (d1i[b] != 1) return;
  float* row = h1 + b * 8450 + (idx % (CC * 13)) * 13;
  float r[13];
#pragma unroll
  for (int k = 0; k < 13; k++) r[k] = row[k];
#pragma unroll
  for (int x = 0; x < 13; x++) {
    float s = bias[x];
    const float* wx = w + x * 13;
#pragma unroll
    for (int k = 0; k < 13; k++) s += r[k] * wx[k];
    row[x] = s;
  }
}

// ---------------- conv3 on h2 (5x5 -> 3x3) + relu + pool2 -> [50,1,1]; d1==0 && d2==0 ----------------
__global__ void k_c32k(const float* __restrict__ h2, const float* __restrict__ w,
                       const float* __restrict__ bias, const int* __restrict__ d1i,
                       const int* __restrict__ d2i, float* __restrict__ c32) {
  int idx = blockIdx.x * 256 + threadIdx.x;
  if (idx >= BB * CC) return;
  int b = idx / CC, oc = idx % CC;
  if (d1i[b] != 0 || d2i[b] != 0) return;
  const float* hb = h2 + b * 1250;
  const float* wb = w + oc * 450;
  float a[4] = {0.f, 0.f, 0.f, 0.f};
  for (int ic = 0; ic < 50; ic++) {
    float r[4][4];
#pragma unroll
    for (int y = 0; y < 4; y++)
#pragma unroll
      for (int x = 0; x < 4; x++) r[y][x] = hb[ic * 25 + y * 5 + x];
    float wv[9];
#pragma unroll
    for (int i = 0; i < 9; i++) wv[i] = wb[ic * 9 + i];
#pragma unroll
    for (int py = 0; py < 2; py++)
#pragma unroll
      for (int px = 0; px < 2; px++) {
        float s = a[py * 2 + px];
#pragma unroll
        for (int ky = 0; ky < 3; ky++)
#pragma unroll
          for (int kx = 0; kx < 3; kx++)
            s += r[py + ky][px + kx] * wv[ky * 3 + kx];
        a[py * 2 + px] = s;
      }
  }
  float m = fmaxf(fmaxf(a[0], a[1]), fmaxf(a[2], a[3]));
  c32[idx] = fmaxf(m + bias[oc], 0.f);
}

// ---------------- head (MFMA v2): block = (sample, half of 256 rows), wave = 64 rows ----------------
// GEMM1: V[256x64]bf16 (bias folded as col 50 = 1.0) @ W1p^T -> H, relu -> GEMM2 vs W2p^T.
// Each wave owns 4 M-tiles: per jt, 2 B-loads feed 8 MFMA (PD2 register prefetch).
// H transposes through per-(wave,mt) LDS tiles; softmax via __shfl_xor over the n-group.
// Verified frag layouts (R6 passed): D col=lane&15, row=(lane>>4)*4+reg; A/B row=lane&15, k=(lane>>4)*8..+8.
__global__ __launch_bounds__(256) void k_head(
    const float* __restrict__ h2, const float* __restrict__ c3d,
    const float* __restrict__ c32, const float* __restrict__ p7,
    const int* __restrict__ d1i, const int* __restrict__ d2i,
    const __bf16* __restrict__ W1p, const __bf16* __restrict__ W2p,
    const float* __restrict__ l2b,
    const float* __restrict__ c1l1w, const float* __restrict__ c1l1b,
    const float* __restrict__ c2l1w, const float* __restrict__ c2l1b,
    float* __restrict__ out) {
  int b = blockIdx.x >> 1;
  int half = blockIdx.x & 1;
  int d1 = d1i[b], d2 = d2i[b];
  int branch, nrows, rstart;
  if (d1 == 2)      { branch = 0; nrows = 500; rstart = 0; }
  else if (d1 == 1) { branch = 3; nrows = 25;  rstart = 667; }
  else if (d2 == 1) { branch = 1; nrows = 166; rstart = 500; }
  else              { branch = 2; nrows = 1;   rstart = 666; }
  int base = half * 256;
  if (base >= nrows) return;
  int nr = nrows - base; if (nr > 256) nr = 256;

  __shared__ __align__(16) __bf16 Vs[256 * 72];     // 36 KB, rows 16B-aligned (stride 144B)
  __shared__ __align__(16) __bf16 Ht[4][4][640];    // 20 KB: [wave][mt][16 rows x 40]
  int t = threadIdx.x;

  for (int idx = t; idx < 256 * 64; idx += 256) {
    int row = idx >> 6, col = idx & 63;
    float val = 0.f;
    if (col == 50) val = 1.0f;
    else if (col < 50 && row < nr) {
      int rr = base + row;
      if (branch == 0) {
        int c = rr / 10; int j = (rr % 10) * 50 + col;
        val = p7[b * 50 + c] * c1l1w[j] + c1l1b[j];
      } else if (branch == 1) {
        int k = rr * 50 + col; int c = k / 166, tt = k % 166;
        const float* hb = h2 + (b * 50 + c) * 25;
        float m = -INFINITY;
        for (int i = 0; i < 3; i++) {
          float a0 = hb[i * 5 + 0], a1 = hb[i * 5 + 1], a2 = hb[i * 5 + 2],
                a3 = hb[i * 5 + 3], a4 = hb[i * 5 + 4];
          for (int dj = 0; dj < 3; dj++) {
            int j = 3 * tt + dj;
            const float* wj = c2l1w + j * 5;
            float s = c2l1b[j] + a0 * wj[0] + a1 * wj[1] + a2 * wj[2] + a3 * wj[3] + a4 * wj[4];
            m = fmaxf(m, s);
          }
        }
        val = m;
      } else if (branch == 2) {
        val = c32[b * 50 + col];
      } else {
        int k = rr * 50 + col; int c = k / 25, s5 = k % 25;
        val = c3d[(b * 50 + c) * 25 + s5];
      }
    }
    Vs[row * 72 + col] = (__bf16)val;
  }
  __syncthreads();

  int wv = t >> 6, lane = t & 63;
  int lr = lane & 15, lg = lane >> 4;
  int wbase = wv * 64;
  if (wbase >= nr) return;            // no barriers after this point
  int wrem = nr - wbase;
  int nmt = (wrem + 15) >> 4; if (nmt > 4) nmt = 4;

  // A1 fragments: 4 M-tiles x 2 K-chunks, read once (ds_read_b128)
  bf16x8 a1[4][2];
#pragma unroll
  for (int mt = 0; mt < 4; ++mt) {
    if (mt < nmt) {
#pragma unroll
      for (int ks = 0; ks < 2; ++ks)
        a1[mt][ks] = *(const bf16x8*)(Vs + (wbase + mt * 16 + lr) * 72 + ks * 32 + lg * 8);
    }
  }

  const __bf16* w1b = W1p + lr * 64 + lg * 8;   // + jt*1024
  const __bf16* w2b = W2p + lr * 512 + lg * 8;  // + q*32
  f32x4 acc2[4];
#pragma unroll
  for (int mt = 0; mt < 4; ++mt) acc2[mt] = (f32x4){0.f, 0.f, 0.f, 0.f};

  bf16x8 pA0 = *(const bf16x8*)(w1b);
  bf16x8 pA1 = *(const bf16x8*)(w1b + 32);
  bf16x8 pB0 = *(const bf16x8*)(w1b + 1024);
  bf16x8 pB1 = *(const bf16x8*)(w1b + 1024 + 32);
  bf16x8 b2n = *(const bf16x8*)(w2b);

  for (int q = 0; q < 16; ++q) {
    // jt = 2q
    {
      bf16x8 b0 = pA0, b1 = pA1;
      if (q < 15) {
        pA0 = *(const bf16x8*)(w1b + (2 * q + 2) * 1024);
        pA1 = *(const bf16x8*)(w1b + (2 * q + 2) * 1024 + 32);
      }
#pragma unroll
      for (int mt = 0; mt < 4; ++mt) {
        if (mt < nmt) {
          f32x4 dz = {0.f, 0.f, 0.f, 0.f};
          f32x4 d = __builtin_amdgcn_mfma_f32_16x16x32_bf16(a1[mt][0], b0, dz, 0, 0, 0);
          d = __builtin_amdgcn_mfma_f32_16x16x32_bf16(a1[mt][1], b1, d, 0, 0, 0);
          __bf16* hp = &Ht[wv][mt][0];
#pragma unroll
          for (int r = 0; r < 4; ++r)
            hp[(lg * 4 + r) * 40 + lr] = (__bf16)fmaxf(d[r], 0.f);
        }
      }
    }
    // jt = 2q+1
    {
      bf16x8 b0 = pB0, b1 = pB1;
      if (q < 15) {
        pB0 = *(const bf16x8*)(w1b + (2 * q + 3) * 1024);
        pB1 = *(const bf16x8*)(w1b + (2 * q + 3) * 1024 + 32);
      }
#pragma unroll
      for (int mt = 0; mt < 4; ++mt) {
        if (mt < nmt) {
          f32x4 dz = {0.f, 0.f, 0.f, 0.f};
          f32x4 d = __builtin_amdgcn_mfma_f32_16x16x32_bf16(a1[mt][0], b0, dz, 0, 0, 0);
          d = __builtin_amdgcn_mfma_f32_16x16x32_bf16(a1[mt][1], b1, d, 0, 0, 0);
          __bf16* hp = &Ht[wv][mt][0];
#pragma unroll
          for (int r = 0; r < 4; ++r)
            hp[(lg * 4 + r) * 40 + 16 + lr] = (__bf16)fmaxf(d[r], 0.f);
        }
      }
    }
    // GEMM2 step for this 32-j window
    {
      bf16x8 bb2 = b2n;
      if (q < 15) b2n = *(const bf16x8*)(w2b + (q + 1) * 32);
#pragma unroll
      for (int mt = 0; mt < 4; ++mt) {
        if (mt < nmt) {
          bf16x8 a2 = *(const bf16x8*)(&Ht[wv][mt][0] + lr * 40 + lg * 8);
          acc2[mt] = __builtin_amdgcn_mfma_f32_16x16x32_bf16(a2, bb2, acc2[mt], 0, 0, 0);
        }
      }
    }
  }

  // log-softmax: lane (lr,lg) holds n=lr for rows wbase + mt*16 + lg*4 + r
  float bl = (lr < 10) ? l2b[lr] : 0.f;
#pragma unroll
  for (int mt = 0; mt < 4; ++mt) {
    if (mt < nmt) {
      float o[4], m[4], s[4];
#pragma unroll
      for (int r = 0; r < 4; ++r) {
        o[r] = acc2[mt][r] + bl;
        m[r] = (lr < 10) ? o[r] : -INFINITY;
      }
#pragma unroll
      for (int mk = 1; mk < 16; mk <<= 1)
#pragma unroll
        for (int r = 0; r < 4; ++r) m[r] = fmaxf(m[r], __shfl_xor(m[r], mk));
#pragma unroll
      for (int r = 0; r < 4; ++r) s[r] = (lr < 10) ? expf(o[r] - m[r]) : 0.f;
#pragma unroll
      for (int mk = 1; mk < 16; mk <<= 1)
#pragma unroll
        for (int r = 0; r < 4; ++r) s[r] += __shfl_xor(s[r], mk);
      if (lr < 10) {
#pragma unroll
        for (int r = 0; r < 4; ++r) {
          int rloc = wbase + mt * 16 + lg * 4 + r;
          if (rloc < nr)
            out[(b * 692 + rstart + base + rloc) * 10 + lr] = o[r] - (m[r] + logf(s[r]));
        }
      }
    }
  }
}

extern "C" void kernel_launch(void* const* d_in, const int* in_sizes, int n_in,
                              void* d_out, int out_size, void* d_ws, size_t ws_size,
                              hipStream_t stream) {
  const float* x     = (const float*)d_in[0];
  const float* c1w   = (const float*)d_in[1];
  const float* c1b   = (const float*)d_in[2];
  const float* c2w   = (const float*)d_in[3];
  const float* c2b   = (const float*)d_in[4];
  const float* c3w   = (const float*)d_in[5];
  const float* c3b   = (const float*)d_in[6];
  const float* l1w   = (const float*)d_in[7];
  const float* l1b   = (const float*)d_in[8];
  const float* l2w   = (const float*)d_in[9];
  const float* l2b   = (const float*)d_in[10];
  const float* d1w   = (const float*)d_in[11];
  const float* d1b   = (const float*)d_in[12];
  const float* d2w   = (const float*)d_in[13];
  const float* d2b   = (const float*)d_in[14];
  const float* c13w  = (const float*)d_in[15];
  const float* c13b  = (const float*)d_in[16];
  const float* c1l1w = (const float*)d_in[17];
  const float* c1l1b = (const float*)d_in[18];
  const float* c2l1w = (const float*)d_in[19];
  const float* c2l1b = (const float*)d_in[20];
  float* out = (float*)d_out;

  float* ws  = (float*)d_ws;
  float* h1  = ws;                 // 4,326,400 floats
  float* h2  = h1 + 4326400;       // 640,000
  float* c3d = h2 + 640000;        // 640,000
  float* c32 = c3d + 640000;       // 25,600
  float* p7  = c32 + 25600;        // 25,600
  int*   d1i = (int*)(p7 + 25600); // 512
  int*   d2i = d1i + 512;          // 512
  __bf16* W1p = (__bf16*)(d2i + 512);   // 512*64 bf16
  __bf16* W2p = W1p + 512 * 64;         // 16*512 bf16

  float* outd1 = out + 512 * 692 * 10;
  float* outd2 = outd1 + 512;

  k_zero<<<3460, 256, 0, stream>>>(out, 885510);
  k_pack<<<160, 256, 0, stream>>>(l1w, l1b, l2w, W1p, W2p);
  k_conv1<<<16900, 256, 0, stream>>>(x, c1w, c1b, h1);
  k_d1<<<512, 256, 0, stream>>>(h1, d1w, d1b, d1i, outd1);
  k_p7<<<100, 256, 0, stream>>>(h1, p7);
  k_conv5<0><<<512, 256, 0, stream>>>(h1, c2w, c2b, d1i, h2);
  k_d2<<<512, 256, 0, stream>>>(h2, d2w, d2b, d2i, outd2);
  k_c33<<<1300, 256, 0, stream>>>(h1, c13w, c13b, d1i);
  k_conv5<1><<<512, 256, 0, stream>>>(h1, c3w, c3b, d1i, c3d);
  k_c32k<<<100, 256, 0, stream>>>(h2, c3w, c3b, d1i, d2i, c32);
  k_head<<<1024, 256, 0, stream>>>(h2, c3d, c32, p7, d1i, d2i,
                                   W1p, W2p, l2b, c1l1w, c1l1b,
                                   c2l1w, c2l1b, out);
}

// Round 8
// 253.586 us; speedup vs baseline: 1.9814x; 1.0710x over previous
//
#include <hip/hip_runtime.h>
#include <hip/hip_bf16.h>
#include <math.h>

#define BB 512
#define CC 50

typedef __attribute__((ext_vector_type(8))) __bf16 bf16x8;
typedef __attribute__((ext_vector_type(4))) float f32x4;

// ---------------- zero-fill out[0 : 512*692*10) ----------------
__global__ void k_zero(float* __restrict__ out, int n4) {
  int i = blockIdx.x * 256 + threadIdx.x;
  if (i < n4) {
    float4 z = {0.f, 0.f, 0.f, 0.f};
    ((float4*)out)[i] = z;
  }
}

// ---------------- pack head weights to bf16 fragments ----------------
// W1p[512 j][64 k]: k<50 = l1w[j][k], k==50 = l1b[j] (bias as K-row), else 0; j>=500 all 0.
// W2p[16 n][512 k2]: n<10 && k2<500 = l2w[n][k2], else 0.
__global__ void k_pack(const float* __restrict__ l1w, const float* __restrict__ l1b,
                       const float* __restrict__ l2w,
                       __bf16* __restrict__ W1p, __bf16* __restrict__ W2p) {
  int idx = blockIdx.x * 256 + threadIdx.x;
  if (idx < 512 * 64) {
    int j = idx >> 6, k = idx & 63;
    float v = 0.f;
    if (j < 500) {
      if (k < 50) v = l1w[j * 50 + k];
      else if (k == 50) v = l1b[j];
    }
    W1p[idx] = (__bf16)v;
  } else if (idx < 512 * 64 + 16 * 512) {
    int i2 = idx - 512 * 64;
    int n = i2 >> 9, k2 = i2 & 511;
    float v = (n < 10 && k2 < 500) ? l2w[n * 500 + k2] : 0.f;
    W2p[i2] = (__bf16)v;
  }
}

// ---------------- conv1 (1->50, 3x3) + relu + pool2 -> h1[512,50,13,13] ----------------
__global__ void k_conv1(const float* __restrict__ x, const float* __restrict__ w,
                        const float* __restrict__ bias, float* __restrict__ h1) {
  int idx = blockIdx.x * 256 + threadIdx.x;
  if (idx >= BB * CC * 169) return;
  int b = idx / (CC * 169);
  int rem = idx % (CC * 169);
  int c = rem / 169;
  int p = rem % 169;
  int py = p / 13, px = p % 13;
  const float* xi = x + b * 784;
  float wr[9];
#pragma unroll
  for (int i = 0; i < 9; i++) wr[i] = w[c * 9 + i];
  float m = -INFINITY;
#pragma unroll
  for (int dy = 0; dy < 2; dy++)
#pragma unroll
    for (int dx = 0; dx < 2; dx++) {
      int y0 = 2 * py + dy, x0 = 2 * px + dx;
      float s = 0.f;
#pragma unroll
      for (int ky = 0; ky < 3; ky++)
#pragma unroll
        for (int kx = 0; kx < 3; kx++)
          s += xi[(y0 + ky) * 28 + x0 + kx] * wr[ky * 3 + kx];
      m = fmaxf(m, s);
    }
  h1[idx] = fmaxf(m + bias[c], 0.f);
}

// ---------------- router 1: argmax over 3 logits of h1 flat (8450) ----------------
__global__ void k_d1(const float* __restrict__ h1, const float* __restrict__ w,
                     const float* __restrict__ bias, int* __restrict__ d1i,
                     float* __restrict__ outd1) {
  int b = blockIdx.x, t = threadIdx.x;
  const float* hb = h1 + b * 8450;
  float s0 = 0.f, s1 = 0.f, s2 = 0.f;
  for (int i = t; i < 8450; i += 256) {
    float v = hb[i];
    s0 += v * w[i];
    s1 += v * w[8450 + i];
    s2 += v * w[16900 + i];
  }
#pragma unroll
  for (int off = 32; off >= 1; off >>= 1) {
    s0 += __shfl_down(s0, off);
    s1 += __shfl_down(s1, off);
    s2 += __shfl_down(s2, off);
  }
  __shared__ float red[4][3];
  if ((t & 63) == 0) { red[t >> 6][0] = s0; red[t >> 6][1] = s1; red[t >> 6][2] = s2; }
  __syncthreads();
  if (t == 0) {
    float l0 = bias[0], l1v = bias[1], l2v = bias[2];
    for (int wv = 0; wv < 4; wv++) { l0 += red[wv][0]; l1v += red[wv][1]; l2v += red[wv][2]; }
    int idx = 0; float best = l0;
    if (l1v > best) { best = l1v; idx = 1; }
    if (l2v > best) { best = l2v; idx = 2; }
    d1i[b] = idx;
    outd1[b] = (float)idx;
  }
}

// ---------------- router 2: argmax over 2 logits of h2 flat (1250) ----------------
__global__ void k_d2(const float* __restrict__ h2, const float* __restrict__ w,
                     const float* __restrict__ bias, int* __restrict__ d2i,
                     float* __restrict__ outd2) {
  int b = blockIdx.x, t = threadIdx.x;
  const float* hb = h2 + b * 1250;
  float s0 = 0.f, s1 = 0.f;
  for (int i = t; i < 1250; i += 256) {
    float v = hb[i];
    s0 += v * w[i];
    s1 += v * w[1250 + i];
  }
#pragma unroll
  for (int off = 32; off >= 1; off >>= 1) {
    s0 += __shfl_down(s0, off);
    s1 += __shfl_down(s1, off);
  }
  __shared__ float red[4][2];
  if ((t & 63) == 0) { red[t >> 6][0] = s0; red[t >> 6][1] = s1; }
  __syncthreads();
  if (t == 0) {
    float l0 = bias[0] + red[0][0] + red[1][0] + red[2][0] + red[3][0];
    float l1v = bias[1] + red[0][1] + red[1][1] + red[2][1] + red[3][1];
    int idx = (l1v > l0) ? 1 : 0;
    d2i[b] = idx;
    outd2[b] = (float)idx;
  }
}

// ---------------- pool7 of h1 (top-left 7x7 window only, VALID) ----------------
__global__ void k_p7(const float* __restrict__ h1, float* __restrict__ p7) {
  int idx = blockIdx.x * 256 + threadIdx.x;
  if (idx >= BB * CC) return;
  int b = idx / CC, c = idx % CC;
  const float* hp = h1 + b * 8450 + c * 169;
  float m = -INFINITY;
#pragma unroll
  for (int y = 0; y < 7; y++)
#pragma unroll
    for (int x = 0; x < 7; x++) m = fmaxf(m, hp[y * 13 + x]);
  p7[idx] = m;
}

// ---------------- 50ch 3x3 conv (13x13 -> 11x11) + relu + pool2 -> [50,5,5] ----------------
template <int MODE>
__global__ __launch_bounds__(256) void k_conv5(const float* __restrict__ in,
                                               const float* __restrict__ w,
                                               const float* __restrict__ bias,
                                               const int* __restrict__ d1i,
                                               float* __restrict__ out) {
  int b = blockIdx.x;
  if (MODE == 1 && d1i[b] != 1) return;
  __shared__ float sh[8450];
  for (int i = threadIdx.x; i < 8450; i += 256) sh[i] = in[b * 8450 + i];
  __syncthreads();
  int t = threadIdx.x;
  if (t >= 250) return;
  int oc = t / 5, py = t % 5;
  float acc[5][4];
#pragma unroll
  for (int i = 0; i < 5; i++)
#pragma unroll
    for (int j = 0; j < 4; j++) acc[i][j] = 0.f;
  const float* wb = w + oc * 450;
  for (int ic = 0; ic < 50; ic++) {
    float wv[9];
#pragma unroll
    for (int i = 0; i < 9; i++) wv[i] = wb[ic * 9 + i];
    float r[4][13];
    const float* rp = sh + ic * 169 + 2 * py * 13;
#pragma unroll
    for (int rr = 0; rr < 4; rr++)
#pragma unroll
      for (int cx = 0; cx < 13; cx++) r[rr][cx] = rp[rr * 13 + cx];
#pragma unroll
    for (int px = 0; px < 5; px++)
#pragma unroll
      for (int dy = 0; dy < 2; dy++)
#pragma unroll
        for (int dx = 0; dx < 2; dx++) {
          float s = acc[px][dy * 2 + dx];
          int x0 = 2 * px + dx;
#pragma unroll
          for (int ky = 0; ky < 3; ky++)
#pragma unroll
            for (int kx = 0; kx < 3; kx++)
              s += r[dy + ky][x0 + kx] * wv[ky * 3 + kx];
          acc[px][dy * 2 + dx] = s;
        }
  }
  float bs = bias[oc];
#pragma unroll
  for (int px = 0; px < 5; px++) {
    float m = fmaxf(fmaxf(acc[px][0], acc[px][1]), fmaxf(acc[px][2], acc[px][3]));
    out[((b * 50 + oc) * 5 + py) * 5 + px] = fmaxf(m + bs, 0.f);
  }
}

// ---------------- c33 = Linear(13->13) on last dim of h1, IN PLACE, only d1==1 ----------------
__global__ void k_c33(float* __restrict__ h1, const float* __restrict__ w,
                      const float* __restrict__ bias, const int* __restrict__ d1i) {
  int idx = blockIdx.x * 256 + threadIdx.x;
  if (idx >= BB * CC * 13) return;
  int b = idx / (CC * 13);
  if (d1i[b] != 1) return;
  float* row = h1 + b * 8450 + (idx % (CC * 13)) * 13;
  float r[13];
#pragma unroll
  for (int k = 0; k < 13; k++) r[k] = row[k];
#pragma unroll
  for (int x = 0; x < 13; x++) {
    float s = bias[x];
    const float* wx = w + x * 13;
#pragma unroll
    for (int k = 0; k < 13; k++) s += r[k] * wx[k];
    row[x] = s;
  }
}

// ---------------- conv3 on h2 (5x5 -> 3x3) + relu + pool2 -> [50,1,1]; d1==0 && d2==0 ----------------
__global__ void k_c32k(const float* __restrict__ h2, const float* __restrict__ w,
                       const float* __restrict__ bias, const int* __restrict__ d1i,
                       const int* __restrict__ d2i, float* __restrict__ c32) {
  int idx = blockIdx.x * 256 + threadIdx.x;
  if (idx >= BB * CC) return;
  int b = idx / CC, oc = idx % CC;
  if (d1i[b] != 0 || d2i[b] != 0) return;
  const float* hb = h2 + b * 1250;
  const float* wb = w + oc * 450;
  float a[4] = {0.f, 0.f, 0.f, 0.f};
  for (int ic = 0; ic < 50; ic++) {
    float r[4][4];
#pragma unroll
    for (int y = 0; y < 4; y++)
#pragma unroll
      for (int x = 0; x < 4; x++) r[y][x] = hb[ic * 25 + y * 5 + x];
    float wv[9];
#pragma unroll
    for (int i = 0; i < 9; i++) wv[i] = wb[ic * 9 + i];
#pragma unroll
    for (int py = 0; py < 2; py++)
#pragma unroll
      for (int px = 0; px < 2; px++) {
        float s = a[py * 2 + px];
#pragma unroll
        for (int ky = 0; ky < 3; ky++)
#pragma unroll
          for (int kx = 0; kx < 3; kx++)
            s += r[py + ky][px + kx] * wv[ky * 3 + kx];
        a[py * 2 + px] = s;
      }
  }
  float m = fmaxf(fmaxf(a[0], a[1]), fmaxf(a[2], a[3]));
  c32[idx] = fmaxf(m + bias[oc], 0.f);
}

// ---------------- l12 = maxpool3(Linear5->500(h2)) for d1==0 && d2==1, flat by k ----------------
// All operands staged in LDS: kills the global-latency chains that dominated k_head's fill.
// l12[b*8300 + k] with k = rr*50+col (the exact flat index k_head's fill uses).
__global__ __launch_bounds__(256) void k_l12(const float* __restrict__ h2,
                                             const float* __restrict__ c2l1w,
                                             const float* __restrict__ c2l1b,
                                             const int* __restrict__ d1i,
                                             const int* __restrict__ d2i,
                                             float* __restrict__ l12) {
  int b = blockIdx.x;
  if (d1i[b] != 0 || d2i[b] != 1) return;
  __shared__ float wls[2500];
  __shared__ float bls[500];
  __shared__ float hs[1250];
  int t = threadIdx.x;
  for (int i = t; i < 2500; i += 256) wls[i] = c2l1w[i];
  for (int i = t; i < 500; i += 256) bls[i] = c2l1b[i];
  for (int i = t; i < 1250; i += 256) hs[i] = h2[b * 1250 + i];
  __syncthreads();
  for (int o = t; o < 8300; o += 256) {
    int c = o / 166, tt = o % 166;
    const float* hb = hs + c * 25;
    float m = -INFINITY;
#pragma unroll
    for (int i = 0; i < 3; i++) {
      float a0 = hb[i * 5 + 0], a1 = hb[i * 5 + 1], a2 = hb[i * 5 + 2],
            a3 = hb[i * 5 + 3], a4 = hb[i * 5 + 4];
#pragma unroll
      for (int dj = 0; dj < 3; dj++) {
        int j = 3 * tt + dj;
        const float* wj = wls + j * 5;
        float s = bls[j] + a0 * wj[0] + a1 * wj[1] + a2 * wj[2] + a3 * wj[3] + a4 * wj[4];
        m = fmaxf(m, s);
      }
    }
    l12[b * 8300 + o] = m;
  }
}

// ---------------- head (MFMA v3): block = (sample, half of 256 rows), wave = 64 rows ----------------
// V-fill is now a coalesced copy for ALL branches (l12 precomputed by k_l12).
// Vs and Ht share one LDS union (Vs dead once A-frags are in registers) -> 37 KB -> 4 blocks/CU.
// No early wave returns before the two barriers (guarded instead).
__global__ __launch_bounds__(256) void k_head(
    const float* __restrict__ h2, const float* __restrict__ c3d,
    const float* __restrict__ c32, const float* __restrict__ p7,
    const float* __restrict__ l12buf,
    const int* __restrict__ d1i, const int* __restrict__ d2i,
    const __bf16* __restrict__ W1p, const __bf16* __restrict__ W2p,
    const float* __restrict__ l2b,
    const float* __restrict__ c1l1w, const float* __restrict__ c1l1b,
    float* __restrict__ out) {
  int b = blockIdx.x >> 1;
  int half = blockIdx.x & 1;
  int d1 = d1i[b], d2 = d2i[b];
  int branch, nrows, rstart;
  if (d1 == 2)      { branch = 0; nrows = 500; rstart = 0; }
  else if (d1 == 1) { branch = 3; nrows = 25;  rstart = 667; }
  else if (d2 == 1) { branch = 1; nrows = 166; rstart = 500; }
  else              { branch = 2; nrows = 1;   rstart = 666; }
  int base = half * 256;
  if (base >= nrows) return;
  int nr = nrows - base; if (nr > 256) nr = 256;

  // LDS union: Vs[256][72] bf16 (36.9 KB) during fill/frag-load, then Ht[4][4][640] bf16 (20 KB)
  __shared__ __align__(16) char smem[256 * 72 * 2];
  __bf16* Vs = (__bf16*)smem;
  __bf16* Ht = (__bf16*)smem;
  int t = threadIdx.x;

  for (int idx = t; idx < 256 * 64; idx += 256) {
    int row = idx >> 6, col = idx & 63;
    float val = 0.f;
    if (col == 50) val = 1.0f;
    else if (col < 50 && row < nr) {
      int rr = base + row;
      if (branch == 0) {
        int c = rr / 10; int j = (rr % 10) * 50 + col;
        val = p7[b * 50 + c] * c1l1w[j] + c1l1b[j];
      } else if (branch == 1) {
        val = l12buf[b * 8300 + rr * 50 + col];
      } else if (branch == 2) {
        val = c32[b * 50 + col];
      } else {
        int k = rr * 50 + col; int c = k / 25, s5 = k % 25;
        val = c3d[(b * 50 + c) * 25 + s5];
      }
    }
    Vs[row * 72 + col] = (__bf16)val;
  }
  __syncthreads();

  int wv = t >> 6, lane = t & 63;
  int lr = lane & 15, lg = lane >> 4;
  int wbase = wv * 64;
  bool active = wbase < nr;
  int wrem = active ? (nr - wbase) : 0;
  int nmt = (wrem + 15) >> 4; if (nmt > 4) nmt = 4;

  // A1 fragments: 4 M-tiles x 2 K-chunks, read once (ds_read_b128), then Vs is dead
  bf16x8 a1[4][2];
  if (active) {
#pragma unroll
    for (int mt = 0; mt < 4; ++mt) {
      if (mt < nmt) {
#pragma unroll
        for (int ks = 0; ks < 2; ++ks)
          a1[mt][ks] = *(const bf16x8*)(Vs + (wbase + mt * 16 + lr) * 72 + ks * 32 + lg * 8);
      }
    }
  }
  __syncthreads();   // all waves done with Vs; smem becomes Ht
  if (!active) return;

  const __bf16* w1b = W1p + lr * 64 + lg * 8;   // + jt*1024
  const __bf16* w2b = W2p + lr * 512 + lg * 8;  // + q*32
  f32x4 acc2[4];
#pragma unroll
  for (int mt = 0; mt < 4; ++mt) acc2[mt] = (f32x4){0.f, 0.f, 0.f, 0.f};

  bf16x8 pA0 = *(const bf16x8*)(w1b);
  bf16x8 pA1 = *(const bf16x8*)(w1b + 32);
  bf16x8 pB0 = *(const bf16x8*)(w1b + 1024);
  bf16x8 pB1 = *(const bf16x8*)(w1b + 1024 + 32);
  bf16x8 b2n = *(const bf16x8*)(w2b);

  for (int q = 0; q < 16; ++q) {
    // jt = 2q
    {
      bf16x8 b0 = pA0, b1 = pA1;
      if (q < 15) {
        pA0 = *(const bf16x8*)(w1b + (2 * q + 2) * 1024);
        pA1 = *(const bf16x8*)(w1b + (2 * q + 2) * 1024 + 32);
      }
#pragma unroll
      for (int mt = 0; mt < 4; ++mt) {
        if (mt < nmt) {
          f32x4 dz = {0.f, 0.f, 0.f, 0.f};
          f32x4 d = __builtin_amdgcn_mfma_f32_16x16x32_bf16(a1[mt][0], b0, dz, 0, 0, 0);
          d = __builtin_amdgcn_mfma_f32_16x16x32_bf16(a1[mt][1], b1, d, 0, 0, 0);
          __bf16* hp = Ht + (wv * 4 + mt) * 640;
#pragma unroll
          for (int r = 0; r < 4; ++r)
            hp[(lg * 4 + r) * 40 + lr] = (__bf16)fmaxf(d[r], 0.f);
        }
      }
    }
    // jt = 2q+1
    {
      bf16x8 b0 = pB0, b1 = pB1;
      if (q < 15) {
        pB0 = *(const bf16x8*)(w1b + (2 * q + 3) * 1024);
        pB1 = *(const bf16x8*)(w1b + (2 * q + 3) * 1024 + 32);
      }
#pragma unroll
      for (int mt = 0; mt < 4; ++mt) {
        if (mt < nmt) {
          f32x4 dz = {0.f, 0.f, 0.f, 0.f};
          f32x4 d = __builtin_amdgcn_mfma_f32_16x16x32_bf16(a1[mt][0], b0, dz, 0, 0, 0);
          d = __builtin_amdgcn_mfma_f32_16x16x32_bf16(a1[mt][1], b1, d, 0, 0, 0);
          __bf16* hp = Ht + (wv * 4 + mt) * 640;
#pragma unroll
          for (int r = 0; r < 4; ++r)
            hp[(lg * 4 + r) * 40 + 16 + lr] = (__bf16)fmaxf(d[r], 0.f);
        }
      }
    }
    // GEMM2 step for this 32-j window
    {
      bf16x8 bb2 = b2n;
      if (q < 15) b2n = *(const bf16x8*)(w2b + (q + 1) * 32);
#pragma unroll
      for (int mt = 0; mt < 4; ++mt) {
        if (mt < nmt) {
          bf16x8 a2 = *(const bf16x8*)(Ht + (wv * 4 + mt) * 640 + lr * 40 + lg * 8);
          acc2[mt] = __builtin_amdgcn_mfma_f32_16x16x32_bf16(a2, bb2, acc2[mt], 0, 0, 0);
        }
      }
    }
  }

  // log-softmax: lane (lr,lg) holds n=lr for rows wbase + mt*16 + lg*4 + r
  float bl = (lr < 10) ? l2b[lr] : 0.f;
#pragma unroll
  for (int mt = 0; mt < 4; ++mt) {
    if (mt < nmt) {
      float o[4], m[4], s[4];
#pragma unroll
      for (int r = 0; r < 4; ++r) {
        o[r] = acc2[mt][r] + bl;
        m[r] = (lr < 10) ? o[r] : -INFINITY;
      }
#pragma unroll
      for (int mk = 1; mk < 16; mk <<= 1)
#pragma unroll
        for (int r = 0; r < 4; ++r) m[r] = fmaxf(m[r], __shfl_xor(m[r], mk));
#pragma unroll
      for (int r = 0; r < 4; ++r) s[r] = (lr < 10) ? expf(o[r] - m[r]) : 0.f;
#pragma unroll
      for (int mk = 1; mk < 16; mk <<= 1)
#pragma unroll
        for (int r = 0; r < 4; ++r) s[r] += __shfl_xor(s[r], mk);
      if (lr < 10) {
#pragma unroll
        for (int r = 0; r < 4; ++r) {
          int rloc = wbase + mt * 16 + lg * 4 + r;
          if (rloc < nr)
            out[(b * 692 + rstart + base + rloc) * 10 + lr] = o[r] - (m[r] + logf(s[r]));
        }
      }
    }
  }
}

extern "C" void kernel_launch(void* const* d_in, const int* in_sizes, int n_in,
                              void* d_out, int out_size, void* d_ws, size_t ws_size,
                              hipStream_t stream) {
  const float* x     = (const float*)d_in[0];
  const float* c1w   = (const float*)d_in[1];
  const float* c1b   = (const float*)d_in[2];
  const float* c2w   = (const float*)d_in[3];
  const float* c2b   = (const float*)d_in[4];
  const float* c3w   = (const float*)d_in[5];
  const float* c3b   = (const float*)d_in[6];
  const float* l1w   = (const float*)d_in[7];
  const float* l1b   = (const float*)d_in[8];
  const float* l2w   = (const float*)d_in[9];
  const float* l2b   = (const float*)d_in[10];
  const float* d1w   = (const float*)d_in[11];
  const float* d1b   = (const float*)d_in[12];
  const float* d2w   = (const float*)d_in[13];
  const float* d2b   = (const float*)d_in[14];
  const float* c13w  = (const float*)d_in[15];
  const float* c13b  = (const float*)d_in[16];
  const float* c1l1w = (const float*)d_in[17];
  const float* c1l1b = (const float*)d_in[18];
  const float* c2l1w = (const float*)d_in[19];
  const float* c2l1b = (const float*)d_in[20];
  float* out = (float*)d_out;

  float* ws  = (float*)d_ws;
  float* h1  = ws;                 // 4,326,400 floats
  float* h2  = h1 + 4326400;       // 640,000
  float* c3d = h2 + 640000;        // 640,000
  float* c32 = c3d + 640000;       // 25,600
  float* p7  = c32 + 25600;        // 25,600
  int*   d1i = (int*)(p7 + 25600); // 512
  int*   d2i = d1i + 512;          // 512
  __bf16* W1p = (__bf16*)(d2i + 512);   // 512*64 bf16
  __bf16* W2p = W1p + 512 * 64;         // 16*512 bf16
  // l12buf aliases h1 (4,249,600 <= 4,326,400 floats): k_l12 runs after the
  // last h1 reader (k_conv5<1>), stream order serializes the reuse.
  float* l12buf = h1;

  float* outd1 = out + 512 * 692 * 10;
  float* outd2 = outd1 + 512;

  k_zero<<<3460, 256, 0, stream>>>(out, 885510);
  k_pack<<<160, 256, 0, stream>>>(l1w, l1b, l2w, W1p, W2p);
  k_conv1<<<16900, 256, 0, stream>>>(x, c1w, c1b, h1);
  k_d1<<<512, 256, 0, stream>>>(h1, d1w, d1b, d1i, outd1);
  k_p7<<<100, 256, 0, stream>>>(h1, p7);
  k_conv5<0><<<512, 256, 0, stream>>>(h1, c2w, c2b, d1i, h2);
  k_d2<<<512, 256, 0, stream>>>(h2, d2w, d2b, d2i, outd2);
  k_c33<<<1300, 256, 0, stream>>>(h1, c13w, c13b, d1i);
  k_conv5<1><<<512, 256, 0, stream>>>(h1, c3w, c3b, d1i, c3d);
  k_c32k<<<100, 256, 0, stream>>>(h2, c3w, c3b, d1i, d2i, c32);
  k_l12<<<512, 256, 0, stream>>>(h2, c2l1w, c2l1b, d1i, d2i, l12buf);
  k_head<<<1024, 256, 0, stream>>>(h2, c3d, c32, p7, l12buf, d1i, d2i,
                                   W1p, W2p, l2b, c1l1w, c1l1b, out);
}

// Round 9
// 237.169 us; speedup vs baseline: 2.1186x; 1.0692x over previous
//
#include <hip/hip_runtime.h>
#include <hip/hip_bf16.h>
#include <math.h>

#define BB 512
#define CC 50

typedef __attribute__((ext_vector_type(8))) __bf16 bf16x8;
typedef __attribute__((ext_vector_type(4))) float f32x4;

// ---------------- zero-fill out[0 : 512*692*10) ----------------
__global__ void k_zero(float* __restrict__ out, int n4) {
  int i = blockIdx.x * 256 + threadIdx.x;
  if (i < n4) {
    float4 z = {0.f, 0.f, 0.f, 0.f};
    ((float4*)out)[i] = z;
  }
}

// ---------------- pack head weights to bf16 fragments ----------------
__global__ void k_pack(const float* __restrict__ l1w, const float* __restrict__ l1b,
                       const float* __restrict__ l2w,
                       __bf16* __restrict__ W1p, __bf16* __restrict__ W2p) {
  int idx = blockIdx.x * 256 + threadIdx.x;
  if (idx < 512 * 64) {
    int j = idx >> 6, k = idx & 63;
    float v = 0.f;
    if (j < 500) {
      if (k < 50) v = l1w[j * 50 + k];
      else if (k == 50) v = l1b[j];
    }
    W1p[idx] = (__bf16)v;
  } else if (idx < 512 * 64 + 16 * 512) {
    int i2 = idx - 512 * 64;
    int n = i2 >> 9, k2 = i2 & 511;
    float v = (n < 10 && k2 < 500) ? l2w[n * 500 + k2] : 0.f;
    W2p[i2] = (__bf16)v;
  }
}

// ---------------- conv1 (1->50, 3x3) + relu + pool2 -> h1[512,50,13,13] ----------------
__global__ void k_conv1(const float* __restrict__ x, const float* __restrict__ w,
                        const float* __restrict__ bias, float* __restrict__ h1) {
  int idx = blockIdx.x * 256 + threadIdx.x;
  if (idx >= BB * CC * 169) return;
  int b = idx / (CC * 169);
  int rem = idx % (CC * 169);
  int c = rem / 169;
  int p = rem % 169;
  int py = p / 13, px = p % 13;
  const float* xi = x + b * 784;
  float wr[9];
#pragma unroll
  for (int i = 0; i < 9; i++) wr[i] = w[c * 9 + i];
  float m = -INFINITY;
#pragma unroll
  for (int dy = 0; dy < 2; dy++)
#pragma unroll
    for (int dx = 0; dx < 2; dx++) {
      int y0 = 2 * py + dy, x0 = 2 * px + dx;
      float s = 0.f;
#pragma unroll
      for (int ky = 0; ky < 3; ky++)
#pragma unroll
        for (int kx = 0; kx < 3; kx++)
          s += xi[(y0 + ky) * 28 + x0 + kx] * wr[ky * 3 + kx];
      m = fmaxf(m, s);
    }
  h1[idx] = fmaxf(m + bias[c], 0.f);
}

// ---------------- router 1 (argmax of 3) + pool7, fused ----------------
__global__ void k_d1p7(const float* __restrict__ h1, const float* __restrict__ w,
                       const float* __restrict__ bias, int* __restrict__ d1i,
                       float* __restrict__ outd1, float* __restrict__ p7) {
  int b = blockIdx.x, t = threadIdx.x;
  const float* hb = h1 + b * 8450;
  float s0 = 0.f, s1 = 0.f, s2 = 0.f;
  for (int i = t; i < 8450; i += 256) {
    float v = hb[i];
    s0 += v * w[i];
    s1 += v * w[8450 + i];
    s2 += v * w[16900 + i];
  }
#pragma unroll
  for (int off = 32; off >= 1; off >>= 1) {
    s0 += __shfl_down(s0, off);
    s1 += __shfl_down(s1, off);
    s2 += __shfl_down(s2, off);
  }
  __shared__ float red[4][3];
  if ((t & 63) == 0) { red[t >> 6][0] = s0; red[t >> 6][1] = s1; red[t >> 6][2] = s2; }
  __syncthreads();
  if (t == 0) {
    float l0 = bias[0], l1v = bias[1], l2v = bias[2];
    for (int wv = 0; wv < 4; wv++) { l0 += red[wv][0]; l1v += red[wv][1]; l2v += red[wv][2]; }
    int idx = 0; float best = l0;
    if (l1v > best) { best = l1v; idx = 1; }
    if (l2v > best) { best = l2v; idx = 2; }
    d1i[b] = idx;
    outd1[b] = (float)idx;
  }
  // pool7 phase (independent of d1 result)
  if (t < 50) {
    const float* hp = hb + t * 169;
    float m = -INFINITY;
#pragma unroll
    for (int y = 0; y < 7; y++)
#pragma unroll
      for (int x = 0; x < 7; x++) m = fmaxf(m, hp[y * 13 + x]);
    p7[b * 50 + t] = m;
  }
}

// ---------------- 50ch 3x3 conv (13x13 -> 11x11) + relu + pool2 -> [50,5,5] ----------------
// LDS planes padded: row stride 20 floats (16B-aligned float4 loads, bank-staggered).
// MODE 1: gated d1==1 and applies the 13x13 linear (c33) in LDS before convolving.
template <int MODE>
__global__ __launch_bounds__(256) void k_conv5(const float* __restrict__ in,
                                               const float* __restrict__ w,
                                               const float* __restrict__ bias,
                                               const int* __restrict__ d1i,
                                               const float* __restrict__ w13,
                                               const float* __restrict__ b13,
                                               float* __restrict__ out) {
  int b = blockIdx.x;
  if (MODE == 1 && d1i[b] != 1) return;
  __shared__ float sh[50 * 260];
  __shared__ float w13s[182];
  int t = threadIdx.x;
  for (int i = t; i < 8450; i += 256) {
    int ic = i / 169, r = i % 169;
    int row = r / 13, xx = r % 13;
    sh[ic * 260 + row * 20 + xx] = in[b * 8450 + i];
  }
  if (MODE == 1) {
    for (int i = t; i < 182; i += 256) w13s[i] = (i < 169) ? w13[i] : b13[i - 169];
  }
  __syncthreads();
  if (MODE == 1) {
    // c33: row'[x] = sum_k row[k]*W13[x][k] + b13[x], per (ic,row)
    for (int p = t; p < 650; p += 256) {
      float* row = sh + (p / 13) * 260 + (p % 13) * 20;
      float r[13];
#pragma unroll
      for (int k = 0; k < 13; k++) r[k] = row[k];
#pragma unroll
      for (int xx = 0; xx < 13; xx++) {
        float s = w13s[169 + xx];
#pragma unroll
        for (int k = 0; k < 13; k++) s += r[k] * w13s[xx * 13 + k];
        row[xx] = s;
      }
    }
    __syncthreads();
  }
  if (t >= 250) return;
  int oc = t / 5, py = t % 5;
  float acc[5][4];
#pragma unroll
  for (int i = 0; i < 5; i++)
#pragma unroll
    for (int j = 0; j < 4; j++) acc[i][j] = 0.f;
  const float* wb = w + oc * 450;
  for (int ic = 0; ic < 50; ic++) {
    float wv[9];
#pragma unroll
    for (int i = 0; i < 9; i++) wv[i] = wb[ic * 9 + i];
    float r[4][13];
    const float* rp = sh + ic * 260 + 2 * py * 20;
#pragma unroll
    for (int rr = 0; rr < 4; rr++) {
      const float* p4 = rp + rr * 20;
      float4 q0 = *(const float4*)(p4);
      float4 q1 = *(const float4*)(p4 + 4);
      float4 q2 = *(const float4*)(p4 + 8);
      r[rr][0] = q0.x; r[rr][1] = q0.y; r[rr][2] = q0.z; r[rr][3] = q0.w;
      r[rr][4] = q1.x; r[rr][5] = q1.y; r[rr][6] = q1.z; r[rr][7] = q1.w;
      r[rr][8] = q2.x; r[rr][9] = q2.y; r[rr][10] = q2.z; r[rr][11] = q2.w;
      r[rr][12] = p4[12];
    }
#pragma unroll
    for (int px = 0; px < 5; px++)
#pragma unroll
      for (int dy = 0; dy < 2; dy++)
#pragma unroll
        for (int dx = 0; dx < 2; dx++) {
          float s = acc[px][dy * 2 + dx];
          int x0 = 2 * px + dx;
#pragma unroll
          for (int ky = 0; ky < 3; ky++)
#pragma unroll
            for (int kx = 0; kx < 3; kx++)
              s += r[dy + ky][x0 + kx] * wv[ky * 3 + kx];
          acc[px][dy * 2 + dx] = s;
        }
  }
  float bs = bias[oc];
#pragma unroll
  for (int px = 0; px < 5; px++) {
    float m = fmaxf(fmaxf(acc[px][0], acc[px][1]), fmaxf(acc[px][2], acc[px][3]));
    out[((b * 50 + oc) * 5 + py) * 5 + px] = fmaxf(m + bs, 0.f);
  }
}

// ---------------- fused: router 2 + c32 (d2==0) + l12 (d2==1), h2 staged once ----------------
__global__ __launch_bounds__(256) void k_d2c(const float* __restrict__ h2,
                                             const float* __restrict__ d2w,
                                             const float* __restrict__ d2b,
                                             const float* __restrict__ c3w,
                                             const float* __restrict__ c3b,
                                             const float* __restrict__ c2l1w,
                                             const float* __restrict__ c2l1b,
                                             const int* __restrict__ d1i,
                                             int* __restrict__ d2i,
                                             float* __restrict__ outd2,
                                             float* __restrict__ c32,
                                             float* __restrict__ l12) {
  int b = blockIdx.x, t = threadIdx.x;
  __shared__ float hs[1250];
  __shared__ float wls[2500];
  __shared__ float bls[500];
  __shared__ float red[4][2];
  __shared__ int sd2;
  for (int i = t; i < 1250; i += 256) hs[i] = h2[b * 1250 + i];
  __syncthreads();
  float s0 = 0.f, s1 = 0.f;
  for (int i = t; i < 1250; i += 256) {
    float v = hs[i];
    s0 += v * d2w[i];
    s1 += v * d2w[1250 + i];
  }
#pragma unroll
  for (int off = 32; off >= 1; off >>= 1) {
    s0 += __shfl_down(s0, off);
    s1 += __shfl_down(s1, off);
  }
  if ((t & 63) == 0) { red[t >> 6][0] = s0; red[t >> 6][1] = s1; }
  __syncthreads();
  if (t == 0) {
    float l0 = d2b[0] + red[0][0] + red[1][0] + red[2][0] + red[3][0];
    float l1v = d2b[1] + red[0][1] + red[1][1] + red[2][1] + red[3][1];
    int idx = (l1v > l0) ? 1 : 0;
    d2i[b] = idx;
    outd2[b] = (float)idx;
    sd2 = idx;
  }
  __syncthreads();
  int d2v = sd2;
  if (d1i[b] != 0) return;
  if (d2v == 0) {
    // c32: conv3(h2)+relu+pool2 -> [50]
    if (t < 50) {
      const float* wb = c3w + t * 450;
      float a[4] = {0.f, 0.f, 0.f, 0.f};
      for (int ic = 0; ic < 50; ic++) {
        float r[4][4];
#pragma unroll
        for (int y = 0; y < 4; y++)
#pragma unroll
          for (int xx = 0; xx < 4; xx++) r[y][xx] = hs[ic * 25 + y * 5 + xx];
        float wv[9];
#pragma unroll
        for (int i = 0; i < 9; i++) wv[i] = wb[ic * 9 + i];
#pragma unroll
        for (int py = 0; py < 2; py++)
#pragma unroll
          for (int px = 0; px < 2; px++) {
            float s = a[py * 2 + px];
#pragma unroll
            for (int ky = 0; ky < 3; ky++)
#pragma unroll
              for (int kx = 0; kx < 3; kx++)
                s += r[py + ky][px + kx] * wv[ky * 3 + kx];
            a[py * 2 + px] = s;
          }
      }
      float m = fmaxf(fmaxf(a[0], a[1]), fmaxf(a[2], a[3]));
      c32[b * 50 + t] = fmaxf(m + c3b[t], 0.f);
    }
  } else {
    // l12: maxpool3(Linear5->500) flat by k
    for (int i = t; i < 2500; i += 256) wls[i] = c2l1w[i];
    for (int i = t; i < 500; i += 256) bls[i] = c2l1b[i];
    __syncthreads();
    for (int o = t; o < 8300; o += 256) {
      int c = o / 166, tt = o % 166;
      const float* hb = hs + c * 25;
      float m = -INFINITY;
#pragma unroll
      for (int i = 0; i < 3; i++) {
        float a0 = hb[i * 5 + 0], a1 = hb[i * 5 + 1], a2 = hb[i * 5 + 2],
              a3 = hb[i * 5 + 3], a4 = hb[i * 5 + 4];
#pragma unroll
        for (int dj = 0; dj < 3; dj++) {
          int j = 3 * tt + dj;
          const float* wj = wls + j * 5;
          float s = bls[j] + a0 * wj[0] + a1 * wj[1] + a2 * wj[2] + a3 * wj[3] + a4 * wj[4];
          m = fmaxf(m, s);
        }
      }
      l12[b * 8300 + o] = m;
    }
  }
}

// XOR swizzle for the W1 LDS chunks: spread 128B-strided b128 reads across banks.
// Applied to BOTH the stage-write and the frag-read (G21: same involution both sides).
__device__ __forceinline__ int swz(int byteoff) {
  return byteoff ^ (((byteoff >> 7) & 7) << 4);
}

// ---------------- head (MFMA v4): W1 stream staged per-block in LDS chunks ----------------
// Block = (sample, half of 256 rows), wave = 64 rows (4 M-tiles).
// W1p (64 KB) staged in 4 chunks of 16 KB, double-buffered (T14 issue-early/write-late),
// one barrier per chunk. All waves stage; inactive waves skip MFMA/softmax only.
__global__ __launch_bounds__(256) void k_head(
    const float* __restrict__ h2, const float* __restrict__ c3d,
    const float* __restrict__ c32, const float* __restrict__ p7,
    const float* __restrict__ l12buf,
    const int* __restrict__ d1i, const int* __restrict__ d2i,
    const __bf16* __restrict__ W1p, const __bf16* __restrict__ W2p,
    const float* __restrict__ l2b,
    const float* __restrict__ c1l1w, const float* __restrict__ c1l1b,
    float* __restrict__ out) {
  int b = blockIdx.x >> 1;
  int half = blockIdx.x & 1;
  int d1 = d1i[b], d2 = d2i[b];
  int branch, nrows, rstart;
  if (d1 == 2)      { branch = 0; nrows = 500; rstart = 0; }
  else if (d1 == 1) { branch = 3; nrows = 25;  rstart = 667; }
  else if (d2 == 1) { branch = 1; nrows = 166; rstart = 500; }
  else              { branch = 2; nrows = 1;   rstart = 666; }
  int base = half * 256;
  if (base >= nrows) return;   // whole block exits before any barrier
  int nr = nrows - base; if (nr > 256) nr = 256;

  // LDS union: phase1 Vs[256][72] bf16 (36864 B); phase2 Wst[2][8192] bf16 (32768) + Ht (20480)
  __shared__ __align__(16) char smem[53248];
  __bf16* Vs = (__bf16*)smem;
  char* Wst = smem;
  __bf16* Ht = (__bf16*)(smem + 32768);
  int t = threadIdx.x;

  for (int idx = t; idx < 256 * 64; idx += 256) {
    int row = idx >> 6, col = idx & 63;
    float val = 0.f;
    if (col == 50) val = 1.0f;
    else if (col < 50 && row < nr) {
      int rr = base + row;
      if (branch == 0) {
        int c = rr / 10; int j = (rr % 10) * 50 + col;
        val = p7[b * 50 + c] * c1l1w[j] + c1l1b[j];
      } else if (branch == 1) {
        val = l12buf[b * 8300 + rr * 50 + col];
      } else if (branch == 2) {
        val = c32[b * 50 + col];
      } else {
        int k = rr * 50 + col; int c = k / 25, s5 = k % 25;
        val = c3d[(b * 50 + c) * 25 + s5];
      }
    }
    Vs[row * 72 + col] = (__bf16)val;
  }

  // issue chunk-0 weight loads early (independent of Vs)
  bf16x8 st[4];
  {
    const __bf16* s0 = W1p + t * 32;
#pragma unroll
    for (int i = 0; i < 4; ++i) st[i] = *(const bf16x8*)(s0 + i * 8);
  }
  __syncthreads();   // Vs ready

  int wv = t >> 6, lane = t & 63;
  int lr = lane & 15, lg = lane >> 4;
  int wbase = wv * 64;
  bool active = wbase < nr;
  int wrem = active ? (nr - wbase) : 0;
  int nmt = (wrem + 15) >> 4; if (nmt > 4) nmt = 4;

  bf16x8 a1[4][2];
  if (active) {
#pragma unroll
    for (int mt = 0; mt < 4; ++mt) {
      if (mt < nmt) {
#pragma unroll
        for (int ks = 0; ks < 2; ++ks)
          a1[mt][ks] = *(const bf16x8*)(Vs + (wbase + mt * 16 + lr) * 72 + ks * 32 + lg * 8);
      }
    }
  }
  __syncthreads();   // Vs dead; smem becomes Wst/Ht

  // write chunk 0 (swizzled)
  {
#pragma unroll
    for (int i = 0; i < 4; ++i)
      *(bf16x8*)(Wst + swz(t * 64 + i * 16)) = st[i];
  }
  __syncthreads();   // buf0 ready

  const __bf16* w2b = W2p + lr * 512 + lg * 8;
  f32x4 acc2[4];
#pragma unroll
  for (int mt = 0; mt < 4; ++mt) acc2[mt] = (f32x4){0.f, 0.f, 0.f, 0.f};
  bf16x8 b2n = *(const bf16x8*)(w2b);

  for (int c = 0; c < 4; ++c) {
    if (c < 3) {
      const __bf16* s2 = W1p + (c + 1) * 8192 + t * 32;
#pragma unroll
      for (int i = 0; i < 4; ++i) st[i] = *(const bf16x8*)(s2 + i * 8);
    }
    char* wb = Wst + (c & 1) * 16384;
    if (active) {
#pragma unroll
      for (int ql = 0; ql < 4; ++ql) {
        int q = c * 4 + ql;
        int boff = ql * 4096 + lr * 128 + lg * 16;   // bytes: jl=2*ql tile
        bf16x8 bA0 = *(const bf16x8*)(wb + swz(boff));
        bf16x8 bA1 = *(const bf16x8*)(wb + swz(boff + 64));
        bf16x8 bB0 = *(const bf16x8*)(wb + swz(boff + 2048));
        bf16x8 bB1 = *(const bf16x8*)(wb + swz(boff + 2048 + 64));
        // jA = 2q
#pragma unroll
        for (int mt = 0; mt < 4; ++mt) {
          if (mt < nmt) {
            f32x4 dz = {0.f, 0.f, 0.f, 0.f};
            f32x4 d = __builtin_amdgcn_mfma_f32_16x16x32_bf16(a1[mt][0], bA0, dz, 0, 0, 0);
            d = __builtin_amdgcn_mfma_f32_16x16x32_bf16(a1[mt][1], bA1, d, 0, 0, 0);
            __bf16* hp = Ht + (wv * 4 + mt) * 640;
#pragma unroll
            for (int r = 0; r < 4; ++r)
              hp[(lg * 4 + r) * 40 + lr] = (__bf16)fmaxf(d[r], 0.f);
          }
        }
        // jB = 2q+1
#pragma unroll
        for (int mt = 0; mt < 4; ++mt) {
          if (mt < nmt) {
            f32x4 dz = {0.f, 0.f, 0.f, 0.f};
            f32x4 d = __builtin_amdgcn_mfma_f32_16x16x32_bf16(a1[mt][0], bB0, dz, 0, 0, 0);
            d = __builtin_amdgcn_mfma_f32_16x16x32_bf16(a1[mt][1], bB1, d, 0, 0, 0);
            __bf16* hp = Ht + (wv * 4 + mt) * 640;
#pragma unroll
            for (int r = 0; r < 4; ++r)
              hp[(lg * 4 + r) * 40 + 16 + lr] = (__bf16)fmaxf(d[r], 0.f);
          }
        }
        // GEMM2 over this 32-j window
        {
          bf16x8 bb2 = b2n;
          if (q < 15) b2n = *(const bf16x8*)(w2b + (q + 1) * 32);
#pragma unroll
          for (int mt = 0; mt < 4; ++mt) {
            if (mt < nmt) {
              bf16x8 a2 = *(const bf16x8*)(Ht + (wv * 4 + mt) * 640 + lr * 40 + lg * 8);
              acc2[mt] = __builtin_amdgcn_mfma_f32_16x16x32_bf16(a2, bb2, acc2[mt], 0, 0, 0);
            }
          }
        }
      }
    }
    if (c < 3) {
      char* wd = Wst + (1 - (c & 1)) * 16384;
#pragma unroll
      for (int i = 0; i < 4; ++i)
        *(bf16x8*)(wd + swz(t * 64 + i * 16)) = st[i];
    }
    __syncthreads();
  }
  if (!active) return;

  // log-softmax via 16-lane shuffle groups
  float bl = (lr < 10) ? l2b[lr] : 0.f;
#pragma unroll
  for (int mt = 0; mt < 4; ++mt) {
    if (mt < nmt) {
      float o[4], m[4], s[4];
#pragma unroll
      for (int r = 0; r < 4; ++r) {
        o[r] = acc2[mt][r] + bl;
        m[r] = (lr < 10) ? o[r] : -INFINITY;
      }
#pragma unroll
      for (int mk = 1; mk < 16; mk <<= 1)
#pragma unroll
        for (int r = 0; r < 4; ++r) m[r] = fmaxf(m[r], __shfl_xor(m[r], mk));
#pragma unroll
      for (int r = 0; r < 4; ++r) s[r] = (lr < 10) ? expf(o[r] - m[r]) : 0.f;
#pragma unroll
      for (int mk = 1; mk < 16; mk <<= 1)
#pragma unroll
        for (int r = 0; r < 4; ++r) s[r] += __shfl_xor(s[r], mk);
      if (lr < 10) {
#pragma unroll
        for (int r = 0; r < 4; ++r) {
          int rloc = wbase + mt * 16 + lg * 4 + r;
          if (rloc < nr)
            out[(b * 692 + rstart + base + rloc) * 10 + lr] = o[r] - (m[r] + logf(s[r]));
        }
      }
    }
  }
}

extern "C" void kernel_launch(void* const* d_in, const int* in_sizes, int n_in,
                              void* d_out, int out_size, void* d_ws, size_t ws_size,
                              hipStream_t stream) {
  const float* x     = (const float*)d_in[0];
  const float* c1w   = (const float*)d_in[1];
  const float* c1b   = (const float*)d_in[2];
  const float* c2w   = (const float*)d_in[3];
  const float* c2b   = (const float*)d_in[4];
  const float* c3w   = (const float*)d_in[5];
  const float* c3b   = (const float*)d_in[6];
  const float* l1w   = (const float*)d_in[7];
  const float* l1b   = (const float*)d_in[8];
  const float* l2w   = (const float*)d_in[9];
  const float* l2b   = (const float*)d_in[10];
  const float* d1w   = (const float*)d_in[11];
  const float* d1b   = (const float*)d_in[12];
  const float* d2w   = (const float*)d_in[13];
  const float* d2b   = (const float*)d_in[14];
  const float* c13w  = (const float*)d_in[15];
  const float* c13b  = (const float*)d_in[16];
  const float* c1l1w = (const float*)d_in[17];
  const float* c1l1b = (const float*)d_in[18];
  const float* c2l1w = (const float*)d_in[19];
  const float* c2l1b = (const float*)d_in[20];
  float* out = (float*)d_out;

  float* ws  = (float*)d_ws;
  float* h1  = ws;                 // 4,326,400 floats
  float* h2  = h1 + 4326400;       // 640,000
  float* c3d = h2 + 640000;        // 640,000
  float* c32 = c3d + 640000;       // 25,600
  float* p7  = c32 + 25600;        // 25,600
  int*   d1i = (int*)(p7 + 25600); // 512
  int*   d2i = d1i + 512;          // 512
  __bf16* W1p = (__bf16*)(d2i + 512);   // 512*64 bf16
  __bf16* W2p = W1p + 512 * 64;         // 16*512 bf16
  // l12buf aliases h1: written by k_d2c AFTER the last h1 reader (k_conv5<1>).
  float* l12buf = h1;

  float* outd1 = out + 512 * 692 * 10;
  float* outd2 = outd1 + 512;

  k_zero<<<3460, 256, 0, stream>>>(out, 885510);
  k_pack<<<160, 256, 0, stream>>>(l1w, l1b, l2w, W1p, W2p);
  k_conv1<<<16900, 256, 0, stream>>>(x, c1w, c1b, h1);
  k_d1p7<<<512, 256, 0, stream>>>(h1, d1w, d1b, d1i, outd1, p7);
  k_conv5<0><<<512, 256, 0, stream>>>(h1, c2w, c2b, d1i, c13w, c13b, h2);
  k_conv5<1><<<512, 256, 0, stream>>>(h1, c3w, c3b, d1i, c13w, c13b, c3d);
  k_d2c<<<512, 256, 0, stream>>>(h2, d2w, d2b, c3w, c3b, c2l1w, c2l1b,
                                 d1i, d2i, outd2, c32, l12buf);
  k_head<<<1024, 256, 0, stream>>>(h2, c3d, c32, p7, l12buf, d1i, d2i,
                                   W1p, W2p, l2b, c1l1w, c1l1b, out);
}